// Round 1
// baseline (1403.582 us; speedup 1.0000x reference)
//
#include <hip/hip_runtime.h>
#include <math.h>

constexpr int B_ = 4;
constexpr int C_ = 256;
constexpr int GH = 40, GW = 40, GP = 1600;   // refine-level grid
constexpr int KDIM = C_ * 9;                  // 2304

// ---------------- Stage 1: ori_fe = mean of pooled/resized inputs ----------------
__global__ void fe_kernel(const float* __restrict__ x0, const float* __restrict__ x1,
                          const float* __restrict__ x2, const float* __restrict__ x3,
                          const float* __restrict__ x4, float* __restrict__ fe) {
    int idx = blockIdx.x * 256 + threadIdx.x;           // over B*C*1600
    int w = idx % GW;
    int h = (idx / GW) % GH;
    int bc = idx / GP;
    const float* p0 = x0 + (size_t)bc * 160 * 160;
    float m0 = -INFINITY;
#pragma unroll
    for (int dy = 0; dy < 4; ++dy)
#pragma unroll
        for (int dx = 0; dx < 4; ++dx)
            m0 = fmaxf(m0, p0[(4 * h + dy) * 160 + 4 * w + dx]);
    const float* p1 = x1 + (size_t)bc * 80 * 80;
    float m1 = -INFINITY;
#pragma unroll
    for (int dy = 0; dy < 2; ++dy)
#pragma unroll
        for (int dx = 0; dx < 2; ++dx)
            m1 = fmaxf(m1, p1[(2 * h + dy) * 80 + 2 * w + dx]);
    float v2 = x2[(size_t)bc * GP + h * GW + w];
    float v3 = x3[(size_t)bc * 400 + (h / 2) * 20 + (w / 2)];
    float v4 = x4[(size_t)bc * 100 + (h / 4) * 10 + (w / 4)];
    fe[idx] = (m0 + m1 + v2 + v3 + v4) * 0.2f;
}

// ---------------- Tiled fp32 GEMM: C[b][n][m] = act(sum_k A[b][m][k] * W[n][k] + bias[n]) ----
// IMPLICIT=1: A built on the fly from fe (im2col of 3x3 pad-1 conv on 40x40)
// IMPLICIT=0: A read from S laid out [b][k][m] (k-major)
template <int IMPLICIT>
__global__ __launch_bounds__(256) void gemm_kernel(const float* __restrict__ Asrc,
                                                   const float* __restrict__ Bw,
                                                   const float* __restrict__ bias,
                                                   float* __restrict__ Cout) {
    int m0 = blockIdx.x * 64;   // 25 tiles over 1600 pixels
    int n0 = blockIdx.y * 64;   // 4 tiles over 256 channels
    int b = blockIdx.z;
    int tid = threadIdx.x;

    __shared__ float As[16][64];
    __shared__ float Bs[16][64];

    int kk = tid >> 4;    // loader: k within chunk
    int grp = tid & 15;   // loader: group of 4 consecutive elements
    int mq = tid & 15;    // compute: 4 m's
    int nq = tid >> 4;    // compute: 4 n's

    const float* Ab = Asrc + (size_t)b * (IMPLICIT ? (size_t)C_ * GP : (size_t)KDIM * GP);
    float acc[4][4] = {};   // [n][m]

    for (int k0 = 0; k0 < KDIM; k0 += 16) {
        int k = k0 + kk;
        if (IMPLICIT) {
            int ci = k / 9;
            int t = k - ci * 9;
            int dy = t / 3 - 1;
            int dx = t - (t / 3) * 3 - 1;
            const float* fp = Ab + (size_t)ci * GP;
#pragma unroll
            for (int j = 0; j < 4; ++j) {
                int m = m0 + grp * 4 + j;
                int h = m / GW;
                int w = m - h * GW;
                int y = h + dy, x = w + dx;
                As[kk][grp * 4 + j] =
                    (y >= 0 && y < GH && x >= 0 && x < GW) ? fp[y * GW + x] : 0.f;
            }
        } else {
            float4 v = *reinterpret_cast<const float4*>(Ab + (size_t)k * GP + m0 + grp * 4);
            *reinterpret_cast<float4*>(&As[kk][grp * 4]) = v;
        }
#pragma unroll
        for (int j = 0; j < 4; ++j) {
            Bs[kk][grp * 4 + j] = Bw[(size_t)(n0 + grp * 4 + j) * KDIM + k];
        }
        __syncthreads();
#pragma unroll
        for (int t2 = 0; t2 < 16; ++t2) {
            float4 a4 = *reinterpret_cast<const float4*>(&As[t2][mq * 4]);
            float4 b4 = *reinterpret_cast<const float4*>(&Bs[t2][nq * 4]);
            float av[4] = {a4.x, a4.y, a4.z, a4.w};
            float bv[4] = {b4.x, b4.y, b4.z, b4.w};
#pragma unroll
            for (int i = 0; i < 4; ++i)
#pragma unroll
                for (int j = 0; j < 4; ++j)
                    acc[i][j] += bv[i] * av[j];
        }
        __syncthreads();
    }

    float* Cb = Cout + (size_t)b * C_ * GP;
#pragma unroll
    for (int i = 0; i < 4; ++i) {
        int n = n0 + nq * 4 + i;
        float bsv = bias ? bias[n] : 0.f;
        float4 o;
        o.x = fmaxf(acc[i][0] + bsv, 0.f);
        o.y = fmaxf(acc[i][1] + bsv, 0.f);
        o.z = fmaxf(acc[i][2] + bsv, 0.f);
        o.w = fmaxf(acc[i][3] + bsv, 0.f);
        *reinterpret_cast<float4*>(Cb + (size_t)n * GP + m0 + mq * 4) = o;
    }
}

// ---------------- pts = conv1x1(p1, w_pts_out) + b ----------------
__global__ void pts_kernel(const float* __restrict__ p1, const float* __restrict__ wpo,
                           const float* __restrict__ bpo, float* __restrict__ pts) {
    int idx = blockIdx.x * 256 + threadIdx.x;   // over B*18*1600
    int pix = idx % GP;
    int p = (idx / GP) % 18;
    int b = idx / (GP * 18);
    const float* pb = p1 + (size_t)b * C_ * GP + pix;
    const float* wp = wpo + p * C_;
    float s = bpo[p];
    for (int c = 0; c < C_; ++c) s += pb[(size_t)c * GP] * wp[c];
    pts[idx] = s;
}

// ---------------- bilinear sampling: S[b][c*9+t][pix] ----------------
__global__ void sample_kernel(const float* __restrict__ fe, const float* __restrict__ pts,
                              float* __restrict__ S) {
    int idx = blockIdx.x * 256 + threadIdx.x;   // over B*2304*1600
    int pix = idx % GP;
    int rest = idx / GP;
    int k = rest % KDIM;
    int b = rest / KDIM;
    int c = k / 9;
    int t = k - c * 9;
    int h = pix / GW;
    int w = pix - h * GW;
    const float* pb = pts + (size_t)b * 18 * GP;
    float py = (float)h + pb[(2 * t) * GP + pix];
    float px = (float)w + pb[(2 * t + 1) * GP + pix];
    float y0f = floorf(py), x0f = floorf(px);
    int y0 = (int)y0f, x0 = (int)x0f;
    float wy1 = py - y0f, wx1 = px - x0f;
    float wy0 = 1.f - wy1, wx0 = 1.f - wx1;
    const float* fc = fe + (size_t)(b * C_ + c) * GP;
    auto tap = [&](int yy, int xx) -> float {
        return (yy >= 0 && yy < GH && xx >= 0 && xx < GW) ? fc[yy * GW + xx] : 0.f;
    };
    float v = tap(y0, x0) * wy0 * wx0 + tap(y0, x0 + 1) * wy0 * wx1 +
              tap(y0 + 1, x0) * wy1 * wx0 + tap(y0 + 1, x0 + 1) * wy1 * wx1;
    S[idx] = v;
}

// ---------------- per-level attention map: tanh(relu(conv1)) + tanh(relu(conv2)) ------
__global__ void att_kernel(const float* __restrict__ x, const float* __restrict__ w1,
                           const float* __restrict__ w2, const float* __restrict__ b1,
                           const float* __restrict__ b2, float* __restrict__ Amap, int s) {
    int idx = blockIdx.x * 256 + threadIdx.x;
    int total = B_ * s * s;
    if (idx >= total) return;
    int pix = idx % (s * s);
    int b = idx / (s * s);
    int h = pix / s, w = pix - h * s;
    const float* xb = x + (size_t)b * C_ * s * s;
    float a1 = 0.f, a2 = 0.f;
    for (int ci = 0; ci < C_; ++ci) {
        const float* xc = xb + (size_t)ci * s * s;
        const float* w1c = w1 + ci * 9;
        const float* w2c = w2 + ci * 9;
#pragma unroll
        for (int t = 0; t < 9; ++t) {
            int dy = t / 3 - 1, dx = t % 3 - 1;
            int y = h + dy, xx = w + dx;
            float v = (y >= 0 && y < s && xx >= 0 && xx < s) ? xc[y * s + xx] : 0.f;
            a1 += v * w1c[t];
            a2 += v * w2c[t];
        }
    }
    a1 = tanhf(fmaxf(a1 + b1[0], 0.f));
    a2 = tanhf(fmaxf(a2 + b2[0], 0.f));
    Amap[idx] = a1 + a2;
}

// ---------------- final combine: out = x + nearest(bsf) * Amap ----------------
__global__ void combine_kernel(const float* __restrict__ x, const float* __restrict__ bsf,
                               const float* __restrict__ Amap, float* __restrict__ out, int s) {
    int idx = blockIdx.x * 256 + threadIdx.x;   // over B*C*s*s (always multiple of 256)
    int pix = idx % (s * s);
    int bc = idx / (s * s);
    int b = bc / C_;
    int h = pix / s, w = pix - h * s;
    int hh = h * GH / s, ww = w * GW / s;
    float bv = bsf[(size_t)bc * GP + hh * GW + ww];
    float av = Amap[(size_t)b * s * s + pix];
    out[idx] = x[idx] + bv * av;
}

extern "C" void kernel_launch(void* const* d_in, const int* in_sizes, int n_in,
                              void* d_out, int out_size, void* d_ws, size_t ws_size,
                              hipStream_t stream) {
    const float* x[5];
    for (int i = 0; i < 5; ++i) x[i] = (const float*)d_in[i];
    const float* w_red1 = (const float*)d_in[5];
    const float* b_red1 = (const float*)d_in[6];
    const float* w_red2 = (const float*)d_in[7];
    const float* b_red2 = (const float*)d_in[8];
    const float* w_pts_conv = (const float*)d_in[9];
    const float* b_pts_conv = (const float*)d_in[10];
    const float* w_pts_out = (const float*)d_in[11];
    const float* b_pts_out = (const float*)d_in[12];
    const float* w_refine = (const float*)d_in[13];
    float* out = (float*)d_out;

    // workspace layout (floats)
    float* ws = (float*)d_ws;
    float* fe = ws;                       // 1,638,400
    float* p1 = fe + 1638400;             // 1,638,400
    float* pts = p1 + 1638400;            //   115,200
    float* bsf = pts + 115200;            // 1,638,400
    float* Amap = bsf + 1638400;          //   102,400
    float* S = Amap + 102400;             // 14,745,600  (total ~79.5 MB)

    static const int SIZES[5] = {160, 80, 40, 20, 10};
    static const size_t OUT_OFF[5] = {0, 26214400, 32768000, 34406400, 34816000};

    fe_kernel<<<6400, 256, 0, stream>>>(x[0], x[1], x[2], x[3], x[4], fe);
    gemm_kernel<1><<<dim3(25, 4, B_), 256, 0, stream>>>(fe, w_pts_conv, b_pts_conv, p1);
    pts_kernel<<<450, 256, 0, stream>>>(p1, w_pts_out, b_pts_out, pts);
    sample_kernel<<<57600, 256, 0, stream>>>(fe, pts, S);
    gemm_kernel<0><<<dim3(25, 4, B_), 256, 0, stream>>>(S, w_refine, nullptr, bsf);

    for (int i = 0; i < 5; ++i) {
        int s = SIZES[i];
        int natt = B_ * s * s;
        att_kernel<<<(natt + 255) / 256, 256, 0, stream>>>(
            x[i], w_red1 + (size_t)i * KDIM, w_red2 + (size_t)i * KDIM,
            b_red1 + i, b_red2 + i, Amap, s);
        int ncmb = B_ * C_ * s * s;
        combine_kernel<<<ncmb / 256, 256, 0, stream>>>(
            x[i], bsf, Amap, out + OUT_OFF[i], s);
    }
}

// Round 5
// 1159.428 us; speedup vs baseline: 1.2106x; 1.2106x over previous
//
#include <hip/hip_runtime.h>
#include <hip/hip_bf16.h>
#include <math.h>

constexpr int B_ = 4;
constexpr int C_ = 256;
constexpr int GH = 40, GW = 40, GP = 1600;   // refine-level grid
constexpr int KDIM = C_ * 9;                  // 2304
constexpr int MT = B_ * GP;                   // 6400

typedef __attribute__((ext_vector_type(8))) short short8b;   // 8 bf16 (4 VGPRs)
typedef __attribute__((ext_vector_type(4))) float f32x4;

__device__ inline ushort f2b(float f) {
    __hip_bfloat16 h = __float2bfloat16(f);
    return *reinterpret_cast<ushort*>(&h);
}

// ---------------- Stage 1: ori_fe = mean of pooled/resized inputs ----------------
__global__ void fe_kernel(const float* __restrict__ x0, const float* __restrict__ x1,
                          const float* __restrict__ x2, const float* __restrict__ x3,
                          const float* __restrict__ x4, float* __restrict__ fe) {
    int idx = blockIdx.x * 256 + threadIdx.x;           // over B*C*1600
    int w = idx % GW;
    int h = (idx / GW) % GH;
    int bc = idx / GP;
    const float* p0 = x0 + (size_t)bc * 160 * 160;
    float m0 = -INFINITY;
#pragma unroll
    for (int dy = 0; dy < 4; ++dy)
#pragma unroll
        for (int dx = 0; dx < 4; ++dx)
            m0 = fmaxf(m0, p0[(4 * h + dy) * 160 + 4 * w + dx]);
    const float* p1 = x1 + (size_t)bc * 80 * 80;
    float m1 = -INFINITY;
#pragma unroll
    for (int dy = 0; dy < 2; ++dy)
#pragma unroll
        for (int dx = 0; dx < 2; ++dx)
            m1 = fmaxf(m1, p1[(2 * h + dy) * 80 + 2 * w + dx]);
    float v2 = x2[(size_t)bc * GP + h * GW + w];
    float v3 = x3[(size_t)bc * 400 + (h / 2) * 20 + (w / 2)];
    float v4 = x4[(size_t)bc * 100 + (h / 4) * 10 + (w / 4)];
    fe[idx] = (m0 + m1 + v2 + v3 + v4) * 0.2f;
}

// ---------------- weight permute+convert: w[o][c*9+t] (fp32) -> Wb[o][t*256+c] (bf16) ----
__global__ void wcvt_kernel(const float* __restrict__ w, ushort* __restrict__ out) {
    int idx = blockIdx.x * 256 + threadIdx.x;   // 256*2304
    int o = idx / KDIM;
    int rem = idx - o * KDIM;
    int c = rem / 9, t = rem - c * 9;
    out[(size_t)o * KDIM + t * 256 + c] = f2b(w[idx]);
}

// ---------------- im2col (3x3 pad1 on fe) -> A1[b*1600+pix][t*256+c] bf16 ----------------
__global__ void im2col_kernel(const float* __restrict__ fe, ushort* __restrict__ A1) {
    int pix = blockIdx.x % GP, b = blockIdx.x / GP;
    int c = threadIdx.x;
    const float* fc = fe + ((size_t)b * C_ + c) * GP;
    ushort* dst = A1 + (size_t)blockIdx.x * KDIM;
    int h = pix / GW, w = pix - (pix / GW) * GW;
#pragma unroll
    for (int t = 0; t < 9; ++t) {
        int y = h + t / 3 - 1, x = w + t % 3 - 1;
        float v = (y >= 0 && y < GH && x >= 0 && x < GW) ? fc[y * GW + x] : 0.f;
        dst[t * 256 + c] = f2b(v);
    }
}

// ---------------- bilinear sampling -> S[b*1600+pix][t*256+c] bf16 ----------------
__global__ void sample_kernel(const float* __restrict__ fe, const float* __restrict__ pts,
                              ushort* __restrict__ S) {
    int pix = blockIdx.x % GP, b = blockIdx.x / GP;
    int c = threadIdx.x;
    const float* fc = fe + ((size_t)b * C_ + c) * GP;
    const float* pb = pts + (size_t)b * 18 * GP + pix;
    ushort* dst = S + (size_t)blockIdx.x * KDIM;
    int h = pix / GW, w = pix - (pix / GW) * GW;
#pragma unroll
    for (int t = 0; t < 9; ++t) {
        float py = (float)h + pb[(2 * t) * GP];
        float px = (float)w + pb[(2 * t + 1) * GP];
        float y0f = floorf(py), x0f = floorf(px);
        int y0 = (int)y0f, x0 = (int)x0f;
        float wy1 = py - y0f, wx1 = px - x0f;
        float wy0 = 1.f - wy1, wx0 = 1.f - wx1;
        auto tap = [&](int yy, int xx) -> float {
            return (yy >= 0 && yy < GH && xx >= 0 && xx < GW) ? fc[yy * GW + xx] : 0.f;
        };
        float v = tap(y0, x0) * wy0 * wx0 + tap(y0, x0 + 1) * wy0 * wx1 +
                  tap(y0 + 1, x0) * wy1 * wx0 + tap(y0 + 1, x0 + 1) * wy1 * wx1;
        dst[t * 256 + c] = f2b(v);
    }
}

// ---------------- bf16 MFMA GEMM: C[b][n][m] = act(sum_k A[bm][k]*W[n][k] (+bias)) ------
// A: [6400][2304] bf16 row-major (k contiguous); W: [256][2304] bf16.
// 64x64 tile, 4 waves 2x2, each wave 32x32 via 2x2 16x16x32 fragments, BK=64.
// LDS XOR-swizzle on 16B slots: phys_slot = slot ^ (row&7)  (write & read identical).
__global__ __launch_bounds__(256) void mfma_gemm(const ushort* __restrict__ A,
                                                 const ushort* __restrict__ Bw,
                                                 const float* __restrict__ bias,
                                                 float* __restrict__ Cout) {
    __shared__ ushort As[64 * 64];
    __shared__ ushort Bs[64 * 64];
    int tid = threadIdx.x;
    int lane = tid & 63;
    int wid = tid >> 6;
    int wm = wid >> 1, wn = wid & 1;
    int m0 = blockIdx.x * 64;
    int n0 = blockIdx.y * 64;

    int sr = tid >> 3;                  // staging row 0..31 (and +32)
    int ss = tid & 7;                   // logical 16B slot 0..7
    int wsl = (ss ^ (sr & 7)) * 8;      // swizzled short offset within row ((sr+32)&7 == sr&7)
    const ushort* gA0 = A + (size_t)(m0 + sr) * KDIM + ss * 8;
    const ushort* gA1 = A + (size_t)(m0 + sr + 32) * KDIM + ss * 8;
    const ushort* gB0 = Bw + (size_t)(n0 + sr) * KDIM + ss * 8;
    const ushort* gB1 = Bw + (size_t)(n0 + sr + 32) * KDIM + ss * 8;

    f32x4 acc[2][2];
#pragma unroll
    for (int i = 0; i < 2; ++i)
#pragma unroll
        for (int j = 0; j < 2; ++j) acc[i][j] = (f32x4){0.f, 0.f, 0.f, 0.f};

    short8b vA0 = *(const short8b*)gA0;
    short8b vA1 = *(const short8b*)gA1;
    short8b vB0 = *(const short8b*)gB0;
    short8b vB1 = *(const short8b*)gB1;

    for (int k0 = 0; k0 < KDIM; k0 += 64) {
        __syncthreads();   // previous compute done before LDS overwrite
        *(short8b*)(As + sr * 64 + wsl) = vA0;
        *(short8b*)(As + (sr + 32) * 64 + wsl) = vA1;
        *(short8b*)(Bs + sr * 64 + wsl) = vB0;
        *(short8b*)(Bs + (sr + 32) * 64 + wsl) = vB1;
        __syncthreads();
        if (k0 + 64 < KDIM) {           // prefetch next tile; latency hides under MFMA
            gA0 += 64; gA1 += 64; gB0 += 64; gB1 += 64;
            vA0 = *(const short8b*)gA0;
            vA1 = *(const short8b*)gA1;
            vB0 = *(const short8b*)gB0;
            vB1 = *(const short8b*)gB1;
        }
#pragma unroll
        for (int kq = 0; kq < 2; ++kq) {
            int k16 = kq * 4 + (lane >> 4);
            short8b af[2], bfr[2];
#pragma unroll
            for (int i = 0; i < 2; ++i) {
                int rA = wm * 32 + i * 16 + (lane & 15);
                af[i] = *(const short8b*)(As + rA * 64 + ((k16 ^ (rA & 7)) * 8));
                int rB = wn * 32 + i * 16 + (lane & 15);
                bfr[i] = *(const short8b*)(Bs + rB * 64 + ((k16 ^ (rB & 7)) * 8));
            }
            // D = Wfrag x Afrag : row=(lane>>4)*4+r -> n, col=lane&15 -> m
#pragma unroll
            for (int in = 0; in < 2; ++in)
#pragma unroll
                for (int im = 0; im < 2; ++im)
                    acc[in][im] = __builtin_amdgcn_mfma_f32_16x16x32_bf16(
                        bfr[in], af[im], acc[in][im], 0, 0, 0);
        }
    }

    int b = m0 / GP;
    int pix0 = m0 - b * GP;     // 1600 % 64 == 0 -> tile never crosses batch
    float* Cb = Cout + (size_t)b * C_ * GP;
#pragma unroll
    for (int in = 0; in < 2; ++in) {
#pragma unroll
        for (int r = 0; r < 4; ++r) {
            int n = n0 + wn * 32 + in * 16 + (lane >> 4) * 4 + r;
            float bv = bias ? bias[n] : 0.f;
#pragma unroll
            for (int im = 0; im < 2; ++im) {
                int m = pix0 + wm * 32 + im * 16 + (lane & 15);
                Cb[(size_t)n * GP + m] = fmaxf(acc[in][im][r] + bv, 0.f);
            }
        }
    }
}

// ---------------- pts = conv1x1(p1, w_pts_out) + b ----------------
__global__ void pts_kernel(const float* __restrict__ p1, const float* __restrict__ wpo,
                           const float* __restrict__ bpo, float* __restrict__ pts) {
    int idx = blockIdx.x * 256 + threadIdx.x;   // over B*18*1600
    int pix = idx % GP;
    int p = (idx / GP) % 18;
    int b = idx / (GP * 18);
    const float* pb = p1 + (size_t)b * C_ * GP + pix;
    const float* wp = wpo + p * C_;
    float s = bpo[p];
    for (int c = 0; c < C_; ++c) s += pb[(size_t)c * GP] * wp[c];
    pts[idx] = s;
}

// ---------------- per-level attention map: tanh(relu(conv1)) + tanh(relu(conv2)) ------
__global__ void att_kernel(const float* __restrict__ x, const float* __restrict__ w1,
                           const float* __restrict__ w2, const float* __restrict__ b1,
                           const float* __restrict__ b2, float* __restrict__ Amap, int s) {
    int idx = blockIdx.x * 256 + threadIdx.x;
    int total = B_ * s * s;
    if (idx >= total) return;
    int pix = idx % (s * s);
    int b = idx / (s * s);
    int h = pix / s, w = pix - h * s;
    const float* xb = x + (size_t)b * C_ * s * s;
    float a1 = 0.f, a2 = 0.f;
    for (int ci = 0; ci < C_; ++ci) {
        const float* xc = xb + (size_t)ci * s * s;
        const float* w1c = w1 + ci * 9;
        const float* w2c = w2 + ci * 9;
#pragma unroll
        for (int t = 0; t < 9; ++t) {
            int dy = t / 3 - 1, dx = t % 3 - 1;
            int y = h + dy, xx = w + dx;
            float v = (y >= 0 && y < s && xx >= 0 && xx < s) ? xc[y * s + xx] : 0.f;
            a1 += v * w1c[t];
            a2 += v * w2c[t];
        }
    }
    a1 = tanhf(fmaxf(a1 + b1[0], 0.f));
    a2 = tanhf(fmaxf(a2 + b2[0], 0.f));
    Amap[idx] = a1 + a2;
}

// ---------------- final combine: out = x + nearest(bsf) * Amap ----------------
__global__ void combine_kernel(const float* __restrict__ x, const float* __restrict__ bsf,
                               const float* __restrict__ Amap, float* __restrict__ out, int s) {
    int idx = blockIdx.x * 256 + threadIdx.x;   // over B*C*s*s (multiple of 256)
    int pix = idx % (s * s);
    int bc = idx / (s * s);
    int b = bc / C_;
    int h = pix / s, w = pix - h * s;
    int hh = h * GH / s, ww = w * GW / s;
    float bv = bsf[(size_t)bc * GP + hh * GW + ww];
    float av = Amap[(size_t)b * s * s + pix];
    out[idx] = x[idx] + bv * av;
}

extern "C" void kernel_launch(void* const* d_in, const int* in_sizes, int n_in,
                              void* d_out, int out_size, void* d_ws, size_t ws_size,
                              hipStream_t stream) {
    const float* x[5];
    for (int i = 0; i < 5; ++i) x[i] = (const float*)d_in[i];
    const float* w_red1 = (const float*)d_in[5];
    const float* b_red1 = (const float*)d_in[6];
    const float* w_red2 = (const float*)d_in[7];
    const float* b_red2 = (const float*)d_in[8];
    const float* w_pts_conv = (const float*)d_in[9];
    const float* b_pts_conv = (const float*)d_in[10];
    const float* w_pts_out = (const float*)d_in[11];
    const float* b_pts_out = (const float*)d_in[12];
    const float* w_refine = (const float*)d_in[13];
    float* out = (float*)d_out;

    // workspace layout
    float* ws = (float*)d_ws;
    float* fe = ws;                        // 1,638,400 f32
    float* p1 = fe + 1638400;              // 1,638,400 f32
    float* pts = p1 + 1638400;             //   115,200 f32
    float* bsf = pts + 115200;             // 1,638,400 f32
    float* Amap = bsf + 1638400;           //   102,400 f32
    ushort* AS_buf = (ushort*)(Amap + 102400);     // 14,745,600 bf16 (A1, then reused for S)
    ushort* Wb1 = AS_buf + (size_t)MT * KDIM;      //   589,824 bf16
    ushort* Wb2 = Wb1 + (size_t)C_ * KDIM;         //   589,824 bf16
    // total ~52.4 MB

    static const int SIZES[5] = {160, 80, 40, 20, 10};
    static const size_t OUT_OFF[5] = {0, 26214400, 32768000, 34406400, 34816000};

    fe_kernel<<<6400, 256, 0, stream>>>(x[0], x[1], x[2], x[3], x[4], fe);
    wcvt_kernel<<<2304, 256, 0, stream>>>(w_pts_conv, Wb1);
    wcvt_kernel<<<2304, 256, 0, stream>>>(w_refine, Wb2);
    im2col_kernel<<<MT, 256, 0, stream>>>(fe, AS_buf);
    mfma_gemm<<<dim3(100, 4), 256, 0, stream>>>(AS_buf, Wb1, b_pts_conv, p1);
    pts_kernel<<<450, 256, 0, stream>>>(p1, w_pts_out, b_pts_out, pts);
    sample_kernel<<<MT, 256, 0, stream>>>(fe, pts, AS_buf);   // overwrites A1
    mfma_gemm<<<dim3(100, 4), 256, 0, stream>>>(AS_buf, Wb2, nullptr, bsf);

    for (int i = 0; i < 5; ++i) {
        int s = SIZES[i];
        int natt = B_ * s * s;
        att_kernel<<<(natt + 255) / 256, 256, 0, stream>>>(
            x[i], w_red1 + (size_t)i * KDIM, w_red2 + (size_t)i * KDIM,
            b_red1 + i, b_red2 + i, Amap, s);
        int ncmb = B_ * C_ * s * s;
        combine_kernel<<<ncmb / 256, 256, 0, stream>>>(
            x[i], bsf, Amap, out + OUT_OFF[i], s);
    }
}

// Round 6
// 955.539 us; speedup vs baseline: 1.4689x; 1.2134x over previous
//
#include <hip/hip_runtime.h>
#include <hip/hip_bf16.h>
#include <math.h>

constexpr int B_ = 4;
constexpr int C_ = 256;
constexpr int GH = 40, GW = 40, GP = 1600;   // refine-level grid
constexpr int KDIM = C_ * 9;                  // 2304
constexpr int MT = B_ * GP;                   // 6400

typedef __attribute__((ext_vector_type(8))) short short8b;   // 8 bf16 (4 VGPRs)
typedef __attribute__((ext_vector_type(4))) float f32x4;

__device__ inline ushort f2b(float f) {
    __hip_bfloat16 h = __float2bfloat16(f);
    return *reinterpret_cast<ushort*>(&h);
}

// ---- Stage 1: ori_fe (PIXEL-MAJOR [b][pix][c]) via LDS transpose ----------------
// Block handles 64 channels x 64 pixels of one batch. Phase 1: compute fe with
// coalesced input reads (lanes along pix). Phase 2: write fe_pm coalesced (lanes along c).
__global__ __launch_bounds__(256) void fe_kernel(const float* __restrict__ x0,
                                                 const float* __restrict__ x1,
                                                 const float* __restrict__ x2,
                                                 const float* __restrict__ x3,
                                                 const float* __restrict__ x4,
                                                 float* __restrict__ fe_pm) {
    __shared__ float tile[64][65];
    int pix0 = blockIdx.x * 64;
    int c0 = blockIdx.y * 64;
    int b = blockIdx.z;
    int lx = threadIdx.x & 63;   // pixel lane
    int ly = threadIdx.x >> 6;   // 4 rows

    int pix = pix0 + lx;
    int h = pix / GW, w = pix - (pix / GW) * GW;
#pragma unroll
    for (int r = 0; r < 64; r += 4) {
        int c = c0 + ly + r;
        size_t bc = (size_t)b * C_ + c;
        const float* p0 = x0 + bc * 25600;
        float m0 = -INFINITY;
#pragma unroll
        for (int dy = 0; dy < 4; ++dy)
#pragma unroll
            for (int dx = 0; dx < 4; ++dx)
                m0 = fmaxf(m0, p0[(4 * h + dy) * 160 + 4 * w + dx]);
        const float* p1 = x1 + bc * 6400;
        float m1 = -INFINITY;
#pragma unroll
        for (int dy = 0; dy < 2; ++dy)
#pragma unroll
            for (int dx = 0; dx < 2; ++dx)
                m1 = fmaxf(m1, p1[(2 * h + dy) * 80 + 2 * w + dx]);
        float v2 = x2[bc * GP + pix];
        float v3 = x3[bc * 400 + (h / 2) * 20 + (w / 2)];
        float v4 = x4[bc * 100 + (h / 4) * 10 + (w / 4)];
        tile[ly + r][lx] = (m0 + m1 + v2 + v3 + v4) * 0.2f;
    }
    __syncthreads();
    // write transposed: lanes along c
#pragma unroll
    for (int r = 0; r < 64; r += 4) {
        int p = ly + r;
        fe_pm[((size_t)b * GP + pix0 + p) * C_ + c0 + lx] = tile[lx][p];
    }
}

// ---- weight permute+convert: w[o][c*9+t] (fp32) -> Wb[o][t*256+c] (bf16) --------
__global__ void wcvt_kernel(const float* __restrict__ w, ushort* __restrict__ out) {
    int idx = blockIdx.x * 256 + threadIdx.x;   // 256*2304
    int o = idx / KDIM;
    int rem = idx - o * KDIM;
    int c = rem / 9, t = rem - c * 9;
    out[(size_t)o * KDIM + t * 256 + c] = f2b(w[idx]);
}

// ---- im2col (3x3 pad1 on fe_pm) -> A1[b*1600+pix][t*256+c] bf16 -----------------
__global__ void im2col_kernel(const float* __restrict__ fe_pm, ushort* __restrict__ A1) {
    int pix = blockIdx.x % GP, b = blockIdx.x / GP;
    int c = threadIdx.x;
    const float* fb = fe_pm + (size_t)b * GP * C_;
    ushort* dst = A1 + (size_t)blockIdx.x * KDIM;
    int h = pix / GW, w = pix - (pix / GW) * GW;
#pragma unroll
    for (int t = 0; t < 9; ++t) {
        int y = h + t / 3 - 1, x = w + t % 3 - 1;
        float v = (y >= 0 && y < GH && x >= 0 && x < GW) ? fb[(size_t)(y * GW + x) * C_ + c]
                                                         : 0.f;
        dst[t * 256 + c] = f2b(v);
    }
}

// ---- bilinear sampling (fe_pm) -> S[b*1600+pix][t*256+c] bf16 -------------------
__global__ void sample_kernel(const float* __restrict__ fe_pm, const float* __restrict__ pts,
                              ushort* __restrict__ S) {
    int pix = blockIdx.x % GP, b = blockIdx.x / GP;
    int c = threadIdx.x;
    const float* fb = fe_pm + (size_t)b * GP * C_;
    const float* pb = pts + (size_t)b * 18 * GP + pix;
    ushort* dst = S + (size_t)blockIdx.x * KDIM;
    int h = pix / GW, w = pix - (pix / GW) * GW;
#pragma unroll
    for (int t = 0; t < 9; ++t) {
        float py = (float)h + pb[(2 * t) * GP];
        float px = (float)w + pb[(2 * t + 1) * GP];
        float y0f = floorf(py), x0f = floorf(px);
        int y0 = (int)y0f, x0 = (int)x0f;
        float wy1 = py - y0f, wx1 = px - x0f;
        float wy0 = 1.f - wy1, wx0 = 1.f - wx1;
        auto tap = [&](int yy, int xx) -> float {
            return (yy >= 0 && yy < GH && xx >= 0 && xx < GW)
                       ? fb[(size_t)(yy * GW + xx) * C_ + c]
                       : 0.f;
        };
        float v = tap(y0, x0) * wy0 * wx0 + tap(y0, x0 + 1) * wy0 * wx1 +
                  tap(y0 + 1, x0) * wy1 * wx0 + tap(y0 + 1, x0 + 1) * wy1 * wx1;
        dst[t * 256 + c] = f2b(v);
    }
}

// ---- bf16 MFMA GEMM: C[b][n][m] = act(sum_k A[bm][k]*W[n][k] (+bias)) -----------
__global__ __launch_bounds__(256) void mfma_gemm(const ushort* __restrict__ A,
                                                 const ushort* __restrict__ Bw,
                                                 const float* __restrict__ bias,
                                                 float* __restrict__ Cout) {
    __shared__ ushort As[64 * 64];
    __shared__ ushort Bs[64 * 64];
    int tid = threadIdx.x;
    int lane = tid & 63;
    int wid = tid >> 6;
    int wm = wid >> 1, wn = wid & 1;
    int m0 = blockIdx.x * 64;
    int n0 = blockIdx.y * 64;

    int sr = tid >> 3;                  // staging row 0..31 (and +32)
    int ss = tid & 7;                   // logical 16B slot 0..7
    int wsl = (ss ^ (sr & 7)) * 8;      // swizzled short offset within row
    const ushort* gA0 = A + (size_t)(m0 + sr) * KDIM + ss * 8;
    const ushort* gA1 = A + (size_t)(m0 + sr + 32) * KDIM + ss * 8;
    const ushort* gB0 = Bw + (size_t)(n0 + sr) * KDIM + ss * 8;
    const ushort* gB1 = Bw + (size_t)(n0 + sr + 32) * KDIM + ss * 8;

    f32x4 acc[2][2];
#pragma unroll
    for (int i = 0; i < 2; ++i)
#pragma unroll
        for (int j = 0; j < 2; ++j) acc[i][j] = (f32x4){0.f, 0.f, 0.f, 0.f};

    short8b vA0 = *(const short8b*)gA0;
    short8b vA1 = *(const short8b*)gA1;
    short8b vB0 = *(const short8b*)gB0;
    short8b vB1 = *(const short8b*)gB1;

    for (int k0 = 0; k0 < KDIM; k0 += 64) {
        __syncthreads();
        *(short8b*)(As + sr * 64 + wsl) = vA0;
        *(short8b*)(As + (sr + 32) * 64 + wsl) = vA1;
        *(short8b*)(Bs + sr * 64 + wsl) = vB0;
        *(short8b*)(Bs + (sr + 32) * 64 + wsl) = vB1;
        __syncthreads();
        if (k0 + 64 < KDIM) {
            gA0 += 64; gA1 += 64; gB0 += 64; gB1 += 64;
            vA0 = *(const short8b*)gA0;
            vA1 = *(const short8b*)gA1;
            vB0 = *(const short8b*)gB0;
            vB1 = *(const short8b*)gB1;
        }
#pragma unroll
        for (int kq = 0; kq < 2; ++kq) {
            int k16 = kq * 4 + (lane >> 4);
            short8b af[2], bfr[2];
#pragma unroll
            for (int i = 0; i < 2; ++i) {
                int rA = wm * 32 + i * 16 + (lane & 15);
                af[i] = *(const short8b*)(As + rA * 64 + ((k16 ^ (rA & 7)) * 8));
                int rB = wn * 32 + i * 16 + (lane & 15);
                bfr[i] = *(const short8b*)(Bs + rB * 64 + ((k16 ^ (rB & 7)) * 8));
            }
#pragma unroll
            for (int in = 0; in < 2; ++in)
#pragma unroll
                for (int im = 0; im < 2; ++im)
                    acc[in][im] = __builtin_amdgcn_mfma_f32_16x16x32_bf16(
                        bfr[in], af[im], acc[in][im], 0, 0, 0);
        }
    }

    int b = m0 / GP;
    int pix0 = m0 - b * GP;
    float* Cb = Cout + (size_t)b * C_ * GP;
#pragma unroll
    for (int in = 0; in < 2; ++in) {
#pragma unroll
        for (int r = 0; r < 4; ++r) {
            int n = n0 + wn * 32 + in * 16 + (lane >> 4) * 4 + r;
            float bv = bias ? bias[n] : 0.f;
#pragma unroll
            for (int im = 0; im < 2; ++im) {
                int m = pix0 + wm * 32 + im * 16 + (lane & 15);
                Cb[(size_t)n * GP + m] = fmaxf(acc[in][im][r] + bv, 0.f);
            }
        }
    }
}

// ---- pts = conv1x1(p1, w_pts_out) + b -------------------------------------------
__global__ void pts_kernel(const float* __restrict__ p1, const float* __restrict__ wpo,
                           const float* __restrict__ bpo, float* __restrict__ pts) {
    int idx = blockIdx.x * 256 + threadIdx.x;   // over B*18*1600
    int pix = idx % GP;
    int p = (idx / GP) % 18;
    int b = idx / (GP * 18);
    const float* pb = p1 + (size_t)b * C_ * GP + pix;
    const float* wp = wpo + p * C_;
    float s = bpo[p];
    for (int c = 0; c < C_; ++c) s += pb[(size_t)c * GP] * wp[c];
    pts[idx] = s;
}

// ---- per-level attention map ----------------------------------------------------
__global__ void att_kernel(const float* __restrict__ x, const float* __restrict__ w1,
                           const float* __restrict__ w2, const float* __restrict__ b1,
                           const float* __restrict__ b2, float* __restrict__ Amap, int s) {
    int idx = blockIdx.x * 256 + threadIdx.x;
    int total = B_ * s * s;
    if (idx >= total) return;
    int pix = idx % (s * s);
    int b = idx / (s * s);
    int h = pix / s, w = pix - h * s;
    const float* xb = x + (size_t)b * C_ * s * s;
    float a1 = 0.f, a2 = 0.f;
    for (int ci = 0; ci < C_; ++ci) {
        const float* xc = xb + (size_t)ci * s * s;
        const float* w1c = w1 + ci * 9;
        const float* w2c = w2 + ci * 9;
#pragma unroll
        for (int t = 0; t < 9; ++t) {
            int dy = t / 3 - 1, dx = t % 3 - 1;
            int y = h + dy, xx = w + dx;
            float v = (y >= 0 && y < s && xx >= 0 && xx < s) ? xc[y * s + xx] : 0.f;
            a1 += v * w1c[t];
            a2 += v * w2c[t];
        }
    }
    a1 = tanhf(fmaxf(a1 + b1[0], 0.f));
    a2 = tanhf(fmaxf(a2 + b2[0], 0.f));
    Amap[idx] = a1 + a2;
}

// ---- final combine: out = x + nearest(bsf) * Amap -------------------------------
__global__ void combine_kernel(const float* __restrict__ x, const float* __restrict__ bsf,
                               const float* __restrict__ Amap, float* __restrict__ out, int s) {
    int idx = blockIdx.x * 256 + threadIdx.x;
    int pix = idx % (s * s);
    int bc = idx / (s * s);
    int b = bc / C_;
    int h = pix / s, w = pix - h * s;
    int hh = h * GH / s, ww = w * GW / s;
    float bv = bsf[(size_t)bc * GP + hh * GW + ww];
    float av = Amap[(size_t)b * s * s + pix];
    out[idx] = x[idx] + bv * av;
}

extern "C" void kernel_launch(void* const* d_in, const int* in_sizes, int n_in,
                              void* d_out, int out_size, void* d_ws, size_t ws_size,
                              hipStream_t stream) {
    const float* x[5];
    for (int i = 0; i < 5; ++i) x[i] = (const float*)d_in[i];
    const float* w_red1 = (const float*)d_in[5];
    const float* b_red1 = (const float*)d_in[6];
    const float* w_red2 = (const float*)d_in[7];
    const float* b_red2 = (const float*)d_in[8];
    const float* w_pts_conv = (const float*)d_in[9];
    const float* b_pts_conv = (const float*)d_in[10];
    const float* w_pts_out = (const float*)d_in[11];
    const float* b_pts_out = (const float*)d_in[12];
    const float* w_refine = (const float*)d_in[13];
    float* out = (float*)d_out;

    // workspace layout
    float* ws = (float*)d_ws;
    float* fe_pm = ws;                     // 1,638,400 f32  [b][pix][c]
    float* p1 = fe_pm + 1638400;           // 1,638,400 f32
    float* pts = p1 + 1638400;             //   115,200 f32
    float* bsf = pts + 115200;             // 1,638,400 f32
    float* Amap = bsf + 1638400;           //   102,400 f32
    ushort* AS_buf = (ushort*)(Amap + 102400);     // 14,745,600 bf16 (A1, then S)
    ushort* Wb1 = AS_buf + (size_t)MT * KDIM;      //   589,824 bf16
    ushort* Wb2 = Wb1 + (size_t)C_ * KDIM;         //   589,824 bf16

    static const int SIZES[5] = {160, 80, 40, 20, 10};
    static const size_t OUT_OFF[5] = {0, 26214400, 32768000, 34406400, 34816000};

    fe_kernel<<<dim3(25, 4, B_), 256, 0, stream>>>(x[0], x[1], x[2], x[3], x[4], fe_pm);
    wcvt_kernel<<<2304, 256, 0, stream>>>(w_pts_conv, Wb1);
    wcvt_kernel<<<2304, 256, 0, stream>>>(w_refine, Wb2);
    im2col_kernel<<<MT, 256, 0, stream>>>(fe_pm, AS_buf);
    mfma_gemm<<<dim3(100, 4), 256, 0, stream>>>(AS_buf, Wb1, b_pts_conv, p1);
    pts_kernel<<<450, 256, 0, stream>>>(p1, w_pts_out, b_pts_out, pts);
    sample_kernel<<<MT, 256, 0, stream>>>(fe_pm, pts, AS_buf);   // overwrites A1
    mfma_gemm<<<dim3(100, 4), 256, 0, stream>>>(AS_buf, Wb2, nullptr, bsf);

    for (int i = 0; i < 5; ++i) {
        int s = SIZES[i];
        int natt = B_ * s * s;
        att_kernel<<<(natt + 255) / 256, 256, 0, stream>>>(
            x[i], w_red1 + (size_t)i * KDIM, w_red2 + (size_t)i * KDIM,
            b_red1 + i, b_red2 + i, Amap, s);
        int ncmb = B_ * C_ * s * s;
        combine_kernel<<<ncmb / 256, 256, 0, stream>>>(
            x[i], bsf, Amap, out + OUT_OFF[i], s);
    }
}

// Round 7
// 510.109 us; speedup vs baseline: 2.7515x; 1.8732x over previous
//
#include <hip/hip_runtime.h>
#include <hip/hip_bf16.h>
#include <math.h>

constexpr int B_ = 4;
constexpr int C_ = 256;
constexpr int GH = 40, GW = 40, GP = 1600;   // refine-level grid
constexpr int KDIM = C_ * 9;                  // 2304
constexpr int MT = B_ * GP;                   // 6400

typedef __attribute__((ext_vector_type(8))) short short8b;   // 8 bf16 (4 VGPRs)
typedef __attribute__((ext_vector_type(4))) float f32x4;

__device__ inline ushort f2b(float f) {
    __hip_bfloat16 h = __float2bfloat16(f);
    return *reinterpret_cast<ushort*>(&h);
}

// ---- Stage 1: ori_fe (PIXEL-MAJOR [b][pix][c]) via LDS transpose ----------------
__global__ __launch_bounds__(256) void fe_kernel(const float* __restrict__ x0,
                                                 const float* __restrict__ x1,
                                                 const float* __restrict__ x2,
                                                 const float* __restrict__ x3,
                                                 const float* __restrict__ x4,
                                                 float* __restrict__ fe_pm) {
    __shared__ float tile[64][65];
    int pix0 = blockIdx.x * 64;
    int c0 = blockIdx.y * 64;
    int b = blockIdx.z;
    int lx = threadIdx.x & 63;   // pixel lane
    int ly = threadIdx.x >> 6;   // 4 rows

    int pix = pix0 + lx;
    int h = pix / GW, w = pix - (pix / GW) * GW;
#pragma unroll
    for (int r = 0; r < 64; r += 4) {
        int c = c0 + ly + r;
        size_t bc = (size_t)b * C_ + c;
        const float* p0 = x0 + bc * 25600;
        float m0 = -INFINITY;
#pragma unroll
        for (int dy = 0; dy < 4; ++dy)
#pragma unroll
            for (int dx = 0; dx < 4; ++dx)
                m0 = fmaxf(m0, p0[(4 * h + dy) * 160 + 4 * w + dx]);
        const float* p1 = x1 + bc * 6400;
        float m1 = -INFINITY;
#pragma unroll
        for (int dy = 0; dy < 2; ++dy)
#pragma unroll
            for (int dx = 0; dx < 2; ++dx)
                m1 = fmaxf(m1, p1[(2 * h + dy) * 80 + 2 * w + dx]);
        float v2 = x2[bc * GP + pix];
        float v3 = x3[bc * 400 + (h / 2) * 20 + (w / 2)];
        float v4 = x4[bc * 100 + (h / 4) * 10 + (w / 4)];
        tile[ly + r][lx] = (m0 + m1 + v2 + v3 + v4) * 0.2f;
    }
    __syncthreads();
#pragma unroll
    for (int r = 0; r < 64; r += 4) {
        int p = ly + r;
        fe_pm[((size_t)b * GP + pix0 + p) * C_ + c0 + lx] = tile[lx][p];
    }
}

// ---- weight permute+convert: w[o][c*9+t] (fp32) -> Wb[o][t*256+c] (bf16) --------
__global__ void wcvt_kernel(const float* __restrict__ w, ushort* __restrict__ out) {
    int idx = blockIdx.x * 256 + threadIdx.x;   // 256*2304
    int o = idx / KDIM;
    int rem = idx - o * KDIM;
    int c = rem / 9, t = rem - c * 9;
    out[(size_t)o * KDIM + t * 256 + c] = f2b(w[idx]);
}

// ---- im2col (3x3 pad1 on fe_pm) -> A1[b*1600+pix][t*256+c] bf16 -----------------
__global__ void im2col_kernel(const float* __restrict__ fe_pm, ushort* __restrict__ A1) {
    int pix = blockIdx.x % GP, b = blockIdx.x / GP;
    int c = threadIdx.x;
    const float* fb = fe_pm + (size_t)b * GP * C_;
    ushort* dst = A1 + (size_t)blockIdx.x * KDIM;
    int h = pix / GW, w = pix - (pix / GW) * GW;
#pragma unroll
    for (int t = 0; t < 9; ++t) {
        int y = h + t / 3 - 1, x = w + t % 3 - 1;
        float v = (y >= 0 && y < GH && x >= 0 && x < GW) ? fb[(size_t)(y * GW + x) * C_ + c]
                                                         : 0.f;
        dst[t * 256 + c] = f2b(v);
    }
}

// ---- bilinear sampling (fe_pm) -> S[b*1600+pix][t*256+c] bf16 -------------------
__global__ void sample_kernel(const float* __restrict__ fe_pm, const float* __restrict__ pts,
                              ushort* __restrict__ S) {
    int pix = blockIdx.x % GP, b = blockIdx.x / GP;
    int c = threadIdx.x;
    const float* fb = fe_pm + (size_t)b * GP * C_;
    const float* pb = pts + (size_t)b * 18 * GP + pix;
    ushort* dst = S + (size_t)blockIdx.x * KDIM;
    int h = pix / GW, w = pix - (pix / GW) * GW;
#pragma unroll
    for (int t = 0; t < 9; ++t) {
        float py = (float)h + pb[(2 * t) * GP];
        float px = (float)w + pb[(2 * t + 1) * GP];
        float y0f = floorf(py), x0f = floorf(px);
        int y0 = (int)y0f, x0 = (int)x0f;
        float wy1 = py - y0f, wx1 = px - x0f;
        float wy0 = 1.f - wy1, wx0 = 1.f - wx1;
        auto tap = [&](int yy, int xx) -> float {
            return (yy >= 0 && yy < GH && xx >= 0 && xx < GW)
                       ? fb[(size_t)(yy * GW + xx) * C_ + c]
                       : 0.f;
        };
        float v = tap(y0, x0) * wy0 * wx0 + tap(y0, x0 + 1) * wy0 * wx1 +
                  tap(y0 + 1, x0) * wy1 * wx0 + tap(y0 + 1, x0 + 1) * wy1 * wx1;
        dst[t * 256 + c] = f2b(v);
    }
}

// ---- bf16 MFMA GEMM: C[b][n][m] = act(sum_k A[bm][k]*W[n][k] (+bias)) -----------
__global__ __launch_bounds__(256) void mfma_gemm(const ushort* __restrict__ A,
                                                 const ushort* __restrict__ Bw,
                                                 const float* __restrict__ bias,
                                                 float* __restrict__ Cout) {
    __shared__ ushort As[64 * 64];
    __shared__ ushort Bs[64 * 64];
    int tid = threadIdx.x;
    int lane = tid & 63;
    int wid = tid >> 6;
    int wm = wid >> 1, wn = wid & 1;
    int m0 = blockIdx.x * 64;
    int n0 = blockIdx.y * 64;

    int sr = tid >> 3;
    int ss = tid & 7;
    int wsl = (ss ^ (sr & 7)) * 8;
    const ushort* gA0 = A + (size_t)(m0 + sr) * KDIM + ss * 8;
    const ushort* gA1 = A + (size_t)(m0 + sr + 32) * KDIM + ss * 8;
    const ushort* gB0 = Bw + (size_t)(n0 + sr) * KDIM + ss * 8;
    const ushort* gB1 = Bw + (size_t)(n0 + sr + 32) * KDIM + ss * 8;

    f32x4 acc[2][2];
#pragma unroll
    for (int i = 0; i < 2; ++i)
#pragma unroll
        for (int j = 0; j < 2; ++j) acc[i][j] = (f32x4){0.f, 0.f, 0.f, 0.f};

    short8b vA0 = *(const short8b*)gA0;
    short8b vA1 = *(const short8b*)gA1;
    short8b vB0 = *(const short8b*)gB0;
    short8b vB1 = *(const short8b*)gB1;

    for (int k0 = 0; k0 < KDIM; k0 += 64) {
        __syncthreads();
        *(short8b*)(As + sr * 64 + wsl) = vA0;
        *(short8b*)(As + (sr + 32) * 64 + wsl) = vA1;
        *(short8b*)(Bs + sr * 64 + wsl) = vB0;
        *(short8b*)(Bs + (sr + 32) * 64 + wsl) = vB1;
        __syncthreads();
        if (k0 + 64 < KDIM) {
            gA0 += 64; gA1 += 64; gB0 += 64; gB1 += 64;
            vA0 = *(const short8b*)gA0;
            vA1 = *(const short8b*)gA1;
            vB0 = *(const short8b*)gB0;
            vB1 = *(const short8b*)gB1;
        }
#pragma unroll
        for (int kq = 0; kq < 2; ++kq) {
            int k16 = kq * 4 + (lane >> 4);
            short8b af[2], bfr[2];
#pragma unroll
            for (int i = 0; i < 2; ++i) {
                int rA = wm * 32 + i * 16 + (lane & 15);
                af[i] = *(const short8b*)(As + rA * 64 + ((k16 ^ (rA & 7)) * 8));
                int rB = wn * 32 + i * 16 + (lane & 15);
                bfr[i] = *(const short8b*)(Bs + rB * 64 + ((k16 ^ (rB & 7)) * 8));
            }
#pragma unroll
            for (int in = 0; in < 2; ++in)
#pragma unroll
                for (int im = 0; im < 2; ++im)
                    acc[in][im] = __builtin_amdgcn_mfma_f32_16x16x32_bf16(
                        bfr[in], af[im], acc[in][im], 0, 0, 0);
        }
    }

    int b = m0 / GP;
    int pix0 = m0 - b * GP;
    float* Cb = Cout + (size_t)b * C_ * GP;
#pragma unroll
    for (int in = 0; in < 2; ++in) {
#pragma unroll
        for (int r = 0; r < 4; ++r) {
            int n = n0 + wn * 32 + in * 16 + (lane >> 4) * 4 + r;
            float bv = bias ? bias[n] : 0.f;
#pragma unroll
            for (int im = 0; im < 2; ++im) {
                int m = pix0 + wm * 32 + im * 16 + (lane & 15);
                Cb[(size_t)n * GP + m] = fmaxf(acc[in][im][r] + bv, 0.f);
            }
        }
    }
}

// ---- pts = conv1x1(p1, w_pts_out) + b -------------------------------------------
__global__ void pts_kernel(const float* __restrict__ p1, const float* __restrict__ wpo,
                           const float* __restrict__ bpo, float* __restrict__ pts) {
    int idx = blockIdx.x * 256 + threadIdx.x;   // over B*18*1600
    int pix = idx % GP;
    int p = (idx / GP) % 18;
    int b = idx / (GP * 18);
    const float* pb = p1 + (size_t)b * C_ * GP + pix;
    const float* wp = wpo + p * C_;
    float s = bpo[p];
    for (int c = 0; c < C_; ++c) s += pb[(size_t)c * GP] * wp[c];
    pts[idx] = s;
}

// ---- att v2: 64 pixels x 4 channel-groups per block, LDS weights + reduce -------
__global__ __launch_bounds__(256) void att_kernel(const float* __restrict__ x,
                                                  const float* __restrict__ w1,
                                                  const float* __restrict__ w2,
                                                  const float* __restrict__ b1,
                                                  const float* __restrict__ b2,
                                                  float* __restrict__ Amap, int s) {
    __shared__ float w1s[KDIM];
    __shared__ float w2s[KDIM];
    __shared__ float red[2][4][64];
    for (int i = threadIdx.x; i < KDIM; i += 256) {
        w1s[i] = w1[i];
        w2s[i] = w2[i];
    }
    __syncthreads();
    int lane = threadIdx.x & 63;
    int grp = threadIdx.x >> 6;          // wave-uniform channel group
    int total = B_ * s * s;
    int pix_g = blockIdx.x * 64 + lane;
    bool valid = pix_g < total;
    int ss_ = s * s;
    int pg = valid ? pix_g : 0;
    int b = pg / ss_;
    int pix = pg - b * ss_;
    int h = pix / s, w = pix - h * s;
    const float* xb = x + ((size_t)b * C_ + grp * 64) * ss_;
    float a1 = 0.f, a2 = 0.f;
    for (int ci = 0; ci < 64; ++ci) {
        const float* xc = xb + (size_t)ci * ss_;
        const float* w1c = w1s + (grp * 64 + ci) * 9;
        const float* w2c = w2s + (grp * 64 + ci) * 9;
#pragma unroll
        for (int t = 0; t < 9; ++t) {
            int dy = t / 3 - 1, dx = t % 3 - 1;
            int y = h + dy, xx = w + dx;
            float v = (y >= 0 && y < s && xx >= 0 && xx < s) ? xc[y * s + xx] : 0.f;
            a1 += v * w1c[t];
            a2 += v * w2c[t];
        }
    }
    red[0][grp][lane] = a1;
    red[1][grp][lane] = a2;
    __syncthreads();
    if (grp == 0 && valid) {
        float s1 = red[0][0][lane] + red[0][1][lane] + red[0][2][lane] + red[0][3][lane];
        float s2 = red[1][0][lane] + red[1][1][lane] + red[1][2][lane] + red[1][3][lane];
        s1 = tanhf(fmaxf(s1 + b1[0], 0.f));
        s2 = tanhf(fmaxf(s2 + b2[0], 0.f));
        Amap[pix_g] = s1 + s2;
    }
}

// ---- final combine: out = x + nearest(bsf) * Amap -------------------------------
__global__ void combine_kernel(const float* __restrict__ x, const float* __restrict__ bsf,
                               const float* __restrict__ Amap, float* __restrict__ out, int s) {
    int idx = blockIdx.x * 256 + threadIdx.x;
    int pix = idx % (s * s);
    int bc = idx / (s * s);
    int b = bc / C_;
    int h = pix / s, w = pix - h * s;
    int hh = h * GH / s, ww = w * GW / s;
    float bv = bsf[(size_t)bc * GP + hh * GW + ww];
    float av = Amap[(size_t)b * s * s + pix];
    out[idx] = x[idx] + bv * av;
}

extern "C" void kernel_launch(void* const* d_in, const int* in_sizes, int n_in,
                              void* d_out, int out_size, void* d_ws, size_t ws_size,
                              hipStream_t stream) {
    const float* x[5];
    for (int i = 0; i < 5; ++i) x[i] = (const float*)d_in[i];
    const float* w_red1 = (const float*)d_in[5];
    const float* b_red1 = (const float*)d_in[6];
    const float* w_red2 = (const float*)d_in[7];
    const float* b_red2 = (const float*)d_in[8];
    const float* w_pts_conv = (const float*)d_in[9];
    const float* b_pts_conv = (const float*)d_in[10];
    const float* w_pts_out = (const float*)d_in[11];
    const float* b_pts_out = (const float*)d_in[12];
    const float* w_refine = (const float*)d_in[13];
    float* out = (float*)d_out;

    // workspace layout
    float* ws = (float*)d_ws;
    float* fe_pm = ws;                     // 1,638,400 f32  [b][pix][c]
    float* p1 = fe_pm + 1638400;           // 1,638,400 f32
    float* pts = p1 + 1638400;             //   115,200 f32
    float* bsf = pts + 115200;             // 1,638,400 f32
    float* Amap = bsf + 1638400;           //   102,400 f32
    ushort* AS_buf = (ushort*)(Amap + 102400);     // 14,745,600 bf16 (A1, then S)
    ushort* Wb1 = AS_buf + (size_t)MT * KDIM;      //   589,824 bf16
    ushort* Wb2 = Wb1 + (size_t)C_ * KDIM;         //   589,824 bf16

    static const int SIZES[5] = {160, 80, 40, 20, 10};
    static const size_t OUT_OFF[5] = {0, 26214400, 32768000, 34406400, 34816000};

    fe_kernel<<<dim3(25, 4, B_), 256, 0, stream>>>(x[0], x[1], x[2], x[3], x[4], fe_pm);
    wcvt_kernel<<<2304, 256, 0, stream>>>(w_pts_conv, Wb1);
    wcvt_kernel<<<2304, 256, 0, stream>>>(w_refine, Wb2);
    im2col_kernel<<<MT, 256, 0, stream>>>(fe_pm, AS_buf);
    mfma_gemm<<<dim3(100, 4), 256, 0, stream>>>(AS_buf, Wb1, b_pts_conv, p1);
    pts_kernel<<<450, 256, 0, stream>>>(p1, w_pts_out, b_pts_out, pts);
    sample_kernel<<<MT, 256, 0, stream>>>(fe_pm, pts, AS_buf);   // overwrites A1
    mfma_gemm<<<dim3(100, 4), 256, 0, stream>>>(AS_buf, Wb2, nullptr, bsf);

    for (int i = 0; i < 5; ++i) {
        int s = SIZES[i];
        int natt = B_ * s * s;
        att_kernel<<<(natt + 63) / 64, 256, 0, stream>>>(
            x[i], w_red1 + (size_t)i * KDIM, w_red2 + (size_t)i * KDIM,
            b_red1 + i, b_red2 + i, Amap, s);
        int ncmb = B_ * C_ * s * s;
        combine_kernel<<<ncmb / 256, 256, 0, stream>>>(
            x[i], bsf, Amap, out + OUT_OFF[i], s);
    }
}

// Round 8
// 480.928 us; speedup vs baseline: 2.9185x; 1.0607x over previous
//
#include <hip/hip_runtime.h>
#include <hip/hip_bf16.h>
#include <math.h>

constexpr int B_ = 4;
constexpr int C_ = 256;
constexpr int GH = 40, GW = 40, GP = 1600;   // refine-level grid
constexpr int KDIM = C_ * 9;                  // 2304
constexpr int MT = B_ * GP;                   // 6400

typedef __attribute__((ext_vector_type(8))) short short8b;   // 8 bf16 (4 VGPRs)
typedef __attribute__((ext_vector_type(4))) float f32x4;

__device__ inline ushort f2b(float f) {
    __hip_bfloat16 h = __float2bfloat16(f);
    return *reinterpret_cast<ushort*>(&h);
}

// ---- Stage 1: ori_fe (PIXEL-MAJOR [b][pix][c]) via LDS transpose ----------------
__global__ __launch_bounds__(256) void fe_kernel(const float* __restrict__ x0,
                                                 const float* __restrict__ x1,
                                                 const float* __restrict__ x2,
                                                 const float* __restrict__ x3,
                                                 const float* __restrict__ x4,
                                                 float* __restrict__ fe_pm) {
    __shared__ float tile[64][65];
    int pix0 = blockIdx.x * 64;
    int c0 = blockIdx.y * 64;
    int b = blockIdx.z;
    int lx = threadIdx.x & 63;   // pixel lane
    int ly = threadIdx.x >> 6;   // 4 rows

    int pix = pix0 + lx;
    int h = pix / GW, w = pix - (pix / GW) * GW;
#pragma unroll
    for (int r = 0; r < 64; r += 4) {
        int c = c0 + ly + r;
        size_t bc = (size_t)b * C_ + c;
        const float* p0 = x0 + bc * 25600;
        float m0 = -INFINITY;
#pragma unroll
        for (int dy = 0; dy < 4; ++dy)
#pragma unroll
            for (int dx = 0; dx < 4; ++dx)
                m0 = fmaxf(m0, p0[(4 * h + dy) * 160 + 4 * w + dx]);
        const float* p1 = x1 + bc * 6400;
        float m1 = -INFINITY;
#pragma unroll
        for (int dy = 0; dy < 2; ++dy)
#pragma unroll
            for (int dx = 0; dx < 2; ++dx)
                m1 = fmaxf(m1, p1[(2 * h + dy) * 80 + 2 * w + dx]);
        float v2 = x2[bc * GP + pix];
        float v3 = x3[bc * 400 + (h / 2) * 20 + (w / 2)];
        float v4 = x4[bc * 100 + (h / 4) * 10 + (w / 4)];
        tile[ly + r][lx] = (m0 + m1 + v2 + v3 + v4) * 0.2f;
    }
    __syncthreads();
#pragma unroll
    for (int r = 0; r < 64; r += 4) {
        int p = ly + r;
        fe_pm[((size_t)b * GP + pix0 + p) * C_ + c0 + lx] = tile[lx][p];
    }
}

// ---- weight permute+convert: w[o][c*9+t] (fp32) -> Wb[o][t*256+c] (bf16) --------
__global__ void wcvt_kernel(const float* __restrict__ w, ushort* __restrict__ out) {
    int idx = blockIdx.x * 256 + threadIdx.x;   // 256*2304
    int o = idx / KDIM;
    int rem = idx - o * KDIM;
    int c = rem / 9, t = rem - c * 9;
    out[(size_t)o * KDIM + t * 256 + c] = f2b(w[idx]);
}

// ---- im2col (3x3 pad1 on fe_pm) -> A1[b*1600+pix][t*256+c] bf16 -----------------
__global__ void im2col_kernel(const float* __restrict__ fe_pm, ushort* __restrict__ A1) {
    int pix = blockIdx.x % GP, b = blockIdx.x / GP;
    int c = threadIdx.x;
    const float* fb = fe_pm + (size_t)b * GP * C_;
    ushort* dst = A1 + (size_t)blockIdx.x * KDIM;
    int h = pix / GW, w = pix - (pix / GW) * GW;
#pragma unroll
    for (int t = 0; t < 9; ++t) {
        int y = h + t / 3 - 1, x = w + t % 3 - 1;
        float v = (y >= 0 && y < GH && x >= 0 && x < GW) ? fb[(size_t)(y * GW + x) * C_ + c]
                                                         : 0.f;
        dst[t * 256 + c] = f2b(v);
    }
}

// ---- bilinear sampling (fe_pm) -> S[b*1600+pix][t*256+c] bf16 -------------------
__global__ void sample_kernel(const float* __restrict__ fe_pm, const float* __restrict__ pts,
                              ushort* __restrict__ S) {
    int pix = blockIdx.x % GP, b = blockIdx.x / GP;
    int c = threadIdx.x;
    const float* fb = fe_pm + (size_t)b * GP * C_;
    const float* pb = pts + (size_t)b * 18 * GP + pix;
    ushort* dst = S + (size_t)blockIdx.x * KDIM;
    int h = pix / GW, w = pix - (pix / GW) * GW;
#pragma unroll
    for (int t = 0; t < 9; ++t) {
        float py = (float)h + pb[(2 * t) * GP];
        float px = (float)w + pb[(2 * t + 1) * GP];
        float y0f = floorf(py), x0f = floorf(px);
        int y0 = (int)y0f, x0 = (int)x0f;
        float wy1 = py - y0f, wx1 = px - x0f;
        float wy0 = 1.f - wy1, wx0 = 1.f - wx1;
        auto tap = [&](int yy, int xx) -> float {
            return (yy >= 0 && yy < GH && xx >= 0 && xx < GW)
                       ? fb[(size_t)(yy * GW + xx) * C_ + c]
                       : 0.f;
        };
        float v = tap(y0, x0) * wy0 * wx0 + tap(y0, x0 + 1) * wy0 * wx1 +
                  tap(y0 + 1, x0) * wy1 * wx0 + tap(y0 + 1, x0 + 1) * wy1 * wx1;
        dst[t * 256 + c] = f2b(v);
    }
}

// ---- bf16 MFMA GEMM: C[b][n][m] = act(sum_k A[bm][k]*W[n][k] (+bias)) -----------
__global__ __launch_bounds__(256) void mfma_gemm(const ushort* __restrict__ A,
                                                 const ushort* __restrict__ Bw,
                                                 const float* __restrict__ bias,
                                                 float* __restrict__ Cout) {
    __shared__ ushort As[64 * 64];
    __shared__ ushort Bs[64 * 64];
    int tid = threadIdx.x;
    int lane = tid & 63;
    int wid = tid >> 6;
    int wm = wid >> 1, wn = wid & 1;
    int m0 = blockIdx.x * 64;
    int n0 = blockIdx.y * 64;

    int sr = tid >> 3;
    int ss = tid & 7;
    int wsl = (ss ^ (sr & 7)) * 8;
    const ushort* gA0 = A + (size_t)(m0 + sr) * KDIM + ss * 8;
    const ushort* gA1 = A + (size_t)(m0 + sr + 32) * KDIM + ss * 8;
    const ushort* gB0 = Bw + (size_t)(n0 + sr) * KDIM + ss * 8;
    const ushort* gB1 = Bw + (size_t)(n0 + sr + 32) * KDIM + ss * 8;

    f32x4 acc[2][2];
#pragma unroll
    for (int i = 0; i < 2; ++i)
#pragma unroll
        for (int j = 0; j < 2; ++j) acc[i][j] = (f32x4){0.f, 0.f, 0.f, 0.f};

    short8b vA0 = *(const short8b*)gA0;
    short8b vA1 = *(const short8b*)gA1;
    short8b vB0 = *(const short8b*)gB0;
    short8b vB1 = *(const short8b*)gB1;

    for (int k0 = 0; k0 < KDIM; k0 += 64) {
        __syncthreads();
        *(short8b*)(As + sr * 64 + wsl) = vA0;
        *(short8b*)(As + (sr + 32) * 64 + wsl) = vA1;
        *(short8b*)(Bs + sr * 64 + wsl) = vB0;
        *(short8b*)(Bs + (sr + 32) * 64 + wsl) = vB1;
        __syncthreads();
        if (k0 + 64 < KDIM) {
            gA0 += 64; gA1 += 64; gB0 += 64; gB1 += 64;
            vA0 = *(const short8b*)gA0;
            vA1 = *(const short8b*)gA1;
            vB0 = *(const short8b*)gB0;
            vB1 = *(const short8b*)gB1;
        }
#pragma unroll
        for (int kq = 0; kq < 2; ++kq) {
            int k16 = kq * 4 + (lane >> 4);
            short8b af[2], bfr[2];
#pragma unroll
            for (int i = 0; i < 2; ++i) {
                int rA = wm * 32 + i * 16 + (lane & 15);
                af[i] = *(const short8b*)(As + rA * 64 + ((k16 ^ (rA & 7)) * 8));
                int rB = wn * 32 + i * 16 + (lane & 15);
                bfr[i] = *(const short8b*)(Bs + rB * 64 + ((k16 ^ (rB & 7)) * 8));
            }
#pragma unroll
            for (int in = 0; in < 2; ++in)
#pragma unroll
                for (int im = 0; im < 2; ++im)
                    acc[in][im] = __builtin_amdgcn_mfma_f32_16x16x32_bf16(
                        bfr[in], af[im], acc[in][im], 0, 0, 0);
        }
    }

    int b = m0 / GP;
    int pix0 = m0 - b * GP;
    float* Cb = Cout + (size_t)b * C_ * GP;
#pragma unroll
    for (int in = 0; in < 2; ++in) {
#pragma unroll
        for (int r = 0; r < 4; ++r) {
            int n = n0 + wn * 32 + in * 16 + (lane >> 4) * 4 + r;
            float bv = bias ? bias[n] : 0.f;
#pragma unroll
            for (int im = 0; im < 2; ++im) {
                int m = pix0 + wm * 32 + im * 16 + (lane & 15);
                Cb[(size_t)n * GP + m] = fmaxf(acc[in][im][r] + bv, 0.f);
            }
        }
    }
}

// ---- pts = conv1x1(p1, w_pts_out) + b -------------------------------------------
__global__ void pts_kernel(const float* __restrict__ p1, const float* __restrict__ wpo,
                           const float* __restrict__ bpo, float* __restrict__ pts) {
    int idx = blockIdx.x * 256 + threadIdx.x;   // over B*18*1600
    int pix = idx % GP;
    int p = (idx / GP) % 18;
    int b = idx / (GP * 18);
    const float* pb = p1 + (size_t)b * C_ * GP + pix;
    const float* wp = wpo + p * C_;
    float s = bpo[p];
    for (int c = 0; c < C_; ++c) s += pb[(size_t)c * GP] * wp[c];
    pts[idx] = s;
}

// ---- fused att+combine: 16x4 pixel tile x 4 channel-groups per block ------------
// Phase 1: per-group partial conv sums -> LDS reduce -> Amap (64 vals in LDS).
// Phase 2: same block applies out = x + nearest(bsf)*A for 256 ch x 64 px
// (x tile is L2-hot from phase 1).
__global__ __launch_bounds__(256) void attcomb_kernel(const float* __restrict__ x,
                                                      const float* __restrict__ w1,
                                                      const float* __restrict__ w2,
                                                      const float* __restrict__ b1,
                                                      const float* __restrict__ b2,
                                                      const float* __restrict__ bsf,
                                                      float* __restrict__ out,
                                                      int s, int tiles_x) {
    __shared__ float w1s[KDIM];
    __shared__ float w2s[KDIM];
    __shared__ float red[2][4][64];
    __shared__ float amap_s[64];
    for (int i = threadIdx.x; i < KDIM; i += 256) {
        w1s[i] = w1[i];
        w2s[i] = w2[i];
    }
    __syncthreads();
    int lane = threadIdx.x & 63;
    int grp = threadIdx.x >> 6;          // wave-uniform channel group
    int tx = lane & 15, ty = lane >> 4;  // 16x4 tile
    int h = (blockIdx.x / tiles_x) * 4 + ty;
    int w = (blockIdx.x % tiles_x) * 16 + tx;
    int b = blockIdx.y;
    bool valid = (h < s && w < s);
    int hc = valid ? h : 0, wc = valid ? w : 0;
    int ss_ = s * s;
    const float* xb = x + ((size_t)b * C_ + grp * 64) * ss_;
    float a1 = 0.f, a2 = 0.f;
    for (int ci = 0; ci < 64; ++ci) {
        const float* xc = xb + (size_t)ci * ss_;
        const float* w1c = w1s + (grp * 64 + ci) * 9;
        const float* w2c = w2s + (grp * 64 + ci) * 9;
#pragma unroll
        for (int t = 0; t < 9; ++t) {
            int dy = t / 3 - 1, dx = t % 3 - 1;
            int y = hc + dy, xx = wc + dx;
            float v = (y >= 0 && y < s && xx >= 0 && xx < s) ? xc[y * s + xx] : 0.f;
            a1 += v * w1c[t];
            a2 += v * w2c[t];
        }
    }
    red[0][grp][lane] = a1;
    red[1][grp][lane] = a2;
    __syncthreads();
    if (grp == 0) {
        float s1 = red[0][0][lane] + red[0][1][lane] + red[0][2][lane] + red[0][3][lane];
        float s2 = red[1][0][lane] + red[1][1][lane] + red[1][2][lane] + red[1][3][lane];
        s1 = tanhf(fmaxf(s1 + b1[0], 0.f));
        s2 = tanhf(fmaxf(s2 + b2[0], 0.f));
        amap_s[lane] = s1 + s2;
    }
    __syncthreads();
    if (!valid) return;
    float av = amap_s[lane];
    int gh = h * GH / s, gw = w * GW / s;
    const float* bb = bsf + (size_t)b * C_ * GP + gh * GW + gw;
    size_t xoff = (size_t)h * s + w;
    const float* xp = x + ((size_t)b * C_ + grp * 64) * ss_ + xoff;
    float* op = out + ((size_t)b * C_ + grp * 64) * ss_ + xoff;
#pragma unroll 4
    for (int ci = 0; ci < 64; ++ci) {
        int c = grp * 64 + ci;
        float xv = xp[(size_t)ci * ss_];
        float bv = bb[(size_t)c * GP];
        op[(size_t)ci * ss_] = xv + bv * av;
    }
}

extern "C" void kernel_launch(void* const* d_in, const int* in_sizes, int n_in,
                              void* d_out, int out_size, void* d_ws, size_t ws_size,
                              hipStream_t stream) {
    const float* x[5];
    for (int i = 0; i < 5; ++i) x[i] = (const float*)d_in[i];
    const float* w_red1 = (const float*)d_in[5];
    const float* b_red1 = (const float*)d_in[6];
    const float* w_red2 = (const float*)d_in[7];
    const float* b_red2 = (const float*)d_in[8];
    const float* w_pts_conv = (const float*)d_in[9];
    const float* b_pts_conv = (const float*)d_in[10];
    const float* w_pts_out = (const float*)d_in[11];
    const float* b_pts_out = (const float*)d_in[12];
    const float* w_refine = (const float*)d_in[13];
    float* out = (float*)d_out;

    // workspace layout
    float* ws = (float*)d_ws;
    float* fe_pm = ws;                     // 1,638,400 f32  [b][pix][c]
    float* p1 = fe_pm + 1638400;           // 1,638,400 f32
    float* pts = p1 + 1638400;             //   115,200 f32
    float* bsf = pts + 115200;             // 1,638,400 f32
    float* Amap = bsf + 1638400;           //   102,400 f32 (unused now)
    ushort* AS_buf = (ushort*)(Amap + 102400);     // 14,745,600 bf16 (A1, then S)
    ushort* Wb1 = AS_buf + (size_t)MT * KDIM;      //   589,824 bf16
    ushort* Wb2 = Wb1 + (size_t)C_ * KDIM;         //   589,824 bf16

    static const int SIZES[5] = {160, 80, 40, 20, 10};
    static const size_t OUT_OFF[5] = {0, 26214400, 32768000, 34406400, 34816000};

    fe_kernel<<<dim3(25, 4, B_), 256, 0, stream>>>(x[0], x[1], x[2], x[3], x[4], fe_pm);
    wcvt_kernel<<<2304, 256, 0, stream>>>(w_pts_conv, Wb1);
    wcvt_kernel<<<2304, 256, 0, stream>>>(w_refine, Wb2);
    im2col_kernel<<<MT, 256, 0, stream>>>(fe_pm, AS_buf);
    mfma_gemm<<<dim3(100, 4), 256, 0, stream>>>(AS_buf, Wb1, b_pts_conv, p1);
    pts_kernel<<<450, 256, 0, stream>>>(p1, w_pts_out, b_pts_out, pts);
    sample_kernel<<<MT, 256, 0, stream>>>(fe_pm, pts, AS_buf);   // overwrites A1
    mfma_gemm<<<dim3(100, 4), 256, 0, stream>>>(AS_buf, Wb2, nullptr, bsf);

    for (int i = 0; i < 5; ++i) {
        int s = SIZES[i];
        int tiles_x = (s + 15) / 16;
        int tiles_y = (s + 3) / 4;
        attcomb_kernel<<<dim3(tiles_x * tiles_y, B_), 256, 0, stream>>>(
            x[i], w_red1 + (size_t)i * KDIM, w_red2 + (size_t)i * KDIM,
            b_red1 + i, b_red2 + i, bsf, out + OUT_OFF[i], s, tiles_x);
    }
}

// Round 9
// 323.146 us; speedup vs baseline: 4.3435x; 1.4883x over previous
//
#include <hip/hip_runtime.h>
#include <hip/hip_bf16.h>
#include <math.h>

constexpr int B_ = 4;
constexpr int C_ = 256;
constexpr int GH = 40, GW = 40, GP = 1600;   // refine-level grid
constexpr int KDIM = C_ * 9;                  // 2304
constexpr int MT = B_ * GP;                   // 6400

typedef __attribute__((ext_vector_type(8))) short short8b;   // 8 bf16 (4 VGPRs)
typedef __attribute__((ext_vector_type(4))) float f32x4;

__device__ inline ushort f2b(float f) {
    __hip_bfloat16 h = __float2bfloat16(f);
    return *reinterpret_cast<ushort*>(&h);
}
__device__ inline float b2f(ushort u) {
    unsigned v = (unsigned)u << 16;
    return *reinterpret_cast<float*>(&v);
}

// ---- Stage 1: ori_fe (PIXEL-MAJOR [b][pix][c]) via LDS transpose ----------------
__global__ __launch_bounds__(256) void fe_kernel(const float* __restrict__ x0,
                                                 const float* __restrict__ x1,
                                                 const float* __restrict__ x2,
                                                 const float* __restrict__ x3,
                                                 const float* __restrict__ x4,
                                                 float* __restrict__ fe_pm) {
    __shared__ float tile[64][65];
    int pix0 = blockIdx.x * 64;
    int c0 = blockIdx.y * 64;
    int b = blockIdx.z;
    int lx = threadIdx.x & 63;   // pixel lane
    int ly = threadIdx.x >> 6;   // 4 rows

    int pix = pix0 + lx;
    int h = pix / GW, w = pix - (pix / GW) * GW;
#pragma unroll
    for (int r = 0; r < 64; r += 4) {
        int c = c0 + ly + r;
        size_t bc = (size_t)b * C_ + c;
        const float* p0 = x0 + bc * 25600;
        float m0 = -INFINITY;
#pragma unroll
        for (int dy = 0; dy < 4; ++dy)
#pragma unroll
            for (int dx = 0; dx < 4; ++dx)
                m0 = fmaxf(m0, p0[(4 * h + dy) * 160 + 4 * w + dx]);
        const float* p1 = x1 + bc * 6400;
        float m1 = -INFINITY;
#pragma unroll
        for (int dy = 0; dy < 2; ++dy)
#pragma unroll
            for (int dx = 0; dx < 2; ++dx)
                m1 = fmaxf(m1, p1[(2 * h + dy) * 80 + 2 * w + dx]);
        float v2 = x2[bc * GP + pix];
        float v3 = x3[bc * 400 + (h / 2) * 20 + (w / 2)];
        float v4 = x4[bc * 100 + (h / 4) * 10 + (w / 4)];
        tile[ly + r][lx] = (m0 + m1 + v2 + v3 + v4) * 0.2f;
    }
    __syncthreads();
#pragma unroll
    for (int r = 0; r < 64; r += 4) {
        int p = ly + r;
        fe_pm[((size_t)b * GP + pix0 + p) * C_ + c0 + lx] = tile[lx][p];
    }
}

// ---- weight permute+convert: w[o][c*9+t] (fp32) -> Wb[o][t*256+c] (bf16) --------
__global__ void wcvt_kernel(const float* __restrict__ w, ushort* __restrict__ out) {
    int idx = blockIdx.x * 256 + threadIdx.x;   // 256*2304
    int o = idx / KDIM;
    int rem = idx - o * KDIM;
    int c = rem / 9, t = rem - c * 9;
    out[(size_t)o * KDIM + t * 256 + c] = f2b(w[idx]);
}

// ---- im2col (3x3 pad1 on fe_pm) -> A1[b*1600+pix][t*256+c] bf16 -----------------
__global__ void im2col_kernel(const float* __restrict__ fe_pm, ushort* __restrict__ A1) {
    int pix = blockIdx.x % GP, b = blockIdx.x / GP;
    int c = threadIdx.x;
    const float* fb = fe_pm + (size_t)b * GP * C_;
    ushort* dst = A1 + (size_t)blockIdx.x * KDIM;
    int h = pix / GW, w = pix - (pix / GW) * GW;
#pragma unroll
    for (int t = 0; t < 9; ++t) {
        int y = h + t / 3 - 1, x = w + t % 3 - 1;
        float v = (y >= 0 && y < GH && x >= 0 && x < GW) ? fb[(size_t)(y * GW + x) * C_ + c]
                                                         : 0.f;
        dst[t * 256 + c] = f2b(v);
    }
}

// ---- bilinear sampling (fe_pm) -> S[b*1600+pix][t*256+c] bf16 -------------------
__global__ void sample_kernel(const float* __restrict__ fe_pm, const float* __restrict__ pts,
                              ushort* __restrict__ S) {
    int pix = blockIdx.x % GP, b = blockIdx.x / GP;
    int c = threadIdx.x;
    const float* fb = fe_pm + (size_t)b * GP * C_;
    const float* pb = pts + (size_t)b * 18 * GP + pix;
    ushort* dst = S + (size_t)blockIdx.x * KDIM;
    int h = pix / GW, w = pix - (pix / GW) * GW;
#pragma unroll
    for (int t = 0; t < 9; ++t) {
        float py = (float)h + pb[(2 * t) * GP];
        float px = (float)w + pb[(2 * t + 1) * GP];
        float y0f = floorf(py), x0f = floorf(px);
        int y0 = (int)y0f, x0 = (int)x0f;
        float wy1 = py - y0f, wx1 = px - x0f;
        float wy0 = 1.f - wy1, wx0 = 1.f - wx1;
        auto tap = [&](int yy, int xx) -> float {
            return (yy >= 0 && yy < GH && xx >= 0 && xx < GW)
                       ? fb[(size_t)(yy * GW + xx) * C_ + c]
                       : 0.f;
        };
        float v = tap(y0, x0) * wy0 * wx0 + tap(y0, x0 + 1) * wy0 * wx1 +
                  tap(y0 + 1, x0) * wy1 * wx0 + tap(y0 + 1, x0 + 1) * wy1 * wx1;
        dst[t * 256 + c] = f2b(v);
    }
}

// ---- bf16 MFMA GEMM: C[b][n][m] = act(sum_k A[bm][k]*W[n][k] (+bias)) -----------
__global__ __launch_bounds__(256) void mfma_gemm(const ushort* __restrict__ A,
                                                 const ushort* __restrict__ Bw,
                                                 const float* __restrict__ bias,
                                                 float* __restrict__ Cout) {
    __shared__ ushort As[64 * 64];
    __shared__ ushort Bs[64 * 64];
    int tid = threadIdx.x;
    int lane = tid & 63;
    int wid = tid >> 6;
    int wm = wid >> 1, wn = wid & 1;
    int m0 = blockIdx.x * 64;
    int n0 = blockIdx.y * 64;

    int sr = tid >> 3;
    int ss = tid & 7;
    int wsl = (ss ^ (sr & 7)) * 8;
    const ushort* gA0 = A + (size_t)(m0 + sr) * KDIM + ss * 8;
    const ushort* gA1 = A + (size_t)(m0 + sr + 32) * KDIM + ss * 8;
    const ushort* gB0 = Bw + (size_t)(n0 + sr) * KDIM + ss * 8;
    const ushort* gB1 = Bw + (size_t)(n0 + sr + 32) * KDIM + ss * 8;

    f32x4 acc[2][2];
#pragma unroll
    for (int i = 0; i < 2; ++i)
#pragma unroll
        for (int j = 0; j < 2; ++j) acc[i][j] = (f32x4){0.f, 0.f, 0.f, 0.f};

    short8b vA0 = *(const short8b*)gA0;
    short8b vA1 = *(const short8b*)gA1;
    short8b vB0 = *(const short8b*)gB0;
    short8b vB1 = *(const short8b*)gB1;

    for (int k0 = 0; k0 < KDIM; k0 += 64) {
        __syncthreads();
        *(short8b*)(As + sr * 64 + wsl) = vA0;
        *(short8b*)(As + (sr + 32) * 64 + wsl) = vA1;
        *(short8b*)(Bs + sr * 64 + wsl) = vB0;
        *(short8b*)(Bs + (sr + 32) * 64 + wsl) = vB1;
        __syncthreads();
        if (k0 + 64 < KDIM) {
            gA0 += 64; gA1 += 64; gB0 += 64; gB1 += 64;
            vA0 = *(const short8b*)gA0;
            vA1 = *(const short8b*)gA1;
            vB0 = *(const short8b*)gB0;
            vB1 = *(const short8b*)gB1;
        }
#pragma unroll
        for (int kq = 0; kq < 2; ++kq) {
            int k16 = kq * 4 + (lane >> 4);
            short8b af[2], bfr[2];
#pragma unroll
            for (int i = 0; i < 2; ++i) {
                int rA = wm * 32 + i * 16 + (lane & 15);
                af[i] = *(const short8b*)(As + rA * 64 + ((k16 ^ (rA & 7)) * 8));
                int rB = wn * 32 + i * 16 + (lane & 15);
                bfr[i] = *(const short8b*)(Bs + rB * 64 + ((k16 ^ (rB & 7)) * 8));
            }
#pragma unroll
            for (int in = 0; in < 2; ++in)
#pragma unroll
                for (int im = 0; im < 2; ++im)
                    acc[in][im] = __builtin_amdgcn_mfma_f32_16x16x32_bf16(
                        bfr[in], af[im], acc[in][im], 0, 0, 0);
        }
    }

    int b = m0 / GP;
    int pix0 = m0 - b * GP;
    float* Cb = Cout + (size_t)b * C_ * GP;
#pragma unroll
    for (int in = 0; in < 2; ++in) {
#pragma unroll
        for (int r = 0; r < 4; ++r) {
            int n = n0 + wn * 32 + in * 16 + (lane >> 4) * 4 + r;
            float bv = bias ? bias[n] : 0.f;
#pragma unroll
            for (int im = 0; im < 2; ++im) {
                int m = pix0 + wm * 32 + im * 16 + (lane & 15);
                Cb[(size_t)n * GP + m] = fmaxf(acc[in][im][r] + bv, 0.f);
            }
        }
    }
}

// ---- pts = conv1x1(p1, w_pts_out) + b -------------------------------------------
__global__ void pts_kernel(const float* __restrict__ p1, const float* __restrict__ wpo,
                           const float* __restrict__ bpo, float* __restrict__ pts) {
    int idx = blockIdx.x * 256 + threadIdx.x;   // over B*18*1600
    int pix = idx % GP;
    int p = (idx / GP) % 18;
    int b = idx / (GP * 18);
    const float* pb = p1 + (size_t)b * C_ * GP + pix;
    const float* wp = wpo + p * C_;
    float s = bpo[p];
    for (int c = 0; c < C_; ++c) s += pb[(size_t)c * GP] * wp[c];
    pts[idx] = s;
}

// ---- att pass 1: y[g][conv*9+t][bp] = sum_{c in grp} w[c,t] * x[c,bp] -----------
// Pure streaming read of x (no halo, fully coalesced). Weights via uniform s_loads.
__global__ __launch_bounds__(256) void yk_kernel(const float* __restrict__ x,
                                                 const float* __restrict__ w1,
                                                 const float* __restrict__ w2,
                                                 ushort* __restrict__ y, int s) {
    int npx = B_ * s * s;
    int bp = blockIdx.x * 256 + threadIdx.x;
    int g = blockIdx.y;
    if (bp >= npx) return;
    int ss_ = s * s;
    int b = bp / ss_;
    int p = bp - b * ss_;
    const float* xg = x + ((size_t)b * C_ + g * 64) * ss_ + p;
    const float* w1g = w1 + g * 64 * 9;
    const float* w2g = w2 + g * 64 * 9;
    float a1[9] = {}, a2[9] = {};
#pragma unroll 4
    for (int ci = 0; ci < 64; ++ci) {
        float v = xg[(size_t)ci * ss_];
#pragma unroll
        for (int t = 0; t < 9; ++t) {
            a1[t] += w1g[ci * 9 + t] * v;
            a2[t] += w2g[ci * 9 + t] * v;
        }
    }
    ushort* yb = y + bp;
#pragma unroll
    for (int t = 0; t < 9; ++t) {
        yb[(size_t)(g * 18 + t) * npx] = f2b(a1[t]);
        yb[(size_t)(g * 18 + 9 + t) * npx] = f2b(a2[t]);
    }
}

// ---- att pass 2 + combine: A from y taps, then out = x + nearest(bsf)*A ---------
__global__ __launch_bounds__(256) void fincomb_kernel(const float* __restrict__ x,
                                                      const ushort* __restrict__ y,
                                                      const float* __restrict__ b1,
                                                      const float* __restrict__ b2,
                                                      const float* __restrict__ bsf,
                                                      float* __restrict__ out, int s) {
    __shared__ float red[2][4][64];
    __shared__ float amap_s[64];
    int npx = B_ * s * s;
    int lane = threadIdx.x & 63;
    int grp = threadIdx.x >> 6;
    int pix_g = blockIdx.x * 64 + lane;
    bool valid = pix_g < npx;
    int pg = valid ? pix_g : 0;
    int ss_ = s * s;
    int b = pg / ss_;
    int pix = pg - b * ss_;
    int h = pix / s, w = pix - h * s;
    const ushort* yg = y + (size_t)grp * 18 * npx;
    float s1 = 0.f, s2 = 0.f;
#pragma unroll
    for (int t = 0; t < 9; ++t) {
        int dy = t / 3 - 1, dx = t % 3 - 1;
        int hy = h + dy, wx = w + dx;
        if (hy >= 0 && hy < s && wx >= 0 && wx < s) {
            int q = pg + dy * s + dx;
            s1 += b2f(yg[(size_t)t * npx + q]);
            s2 += b2f(yg[(size_t)(9 + t) * npx + q]);
        }
    }
    red[0][grp][lane] = s1;
    red[1][grp][lane] = s2;
    __syncthreads();
    if (grp == 0) {
        float t1 = red[0][0][lane] + red[0][1][lane] + red[0][2][lane] + red[0][3][lane];
        float t2 = red[1][0][lane] + red[1][1][lane] + red[1][2][lane] + red[1][3][lane];
        t1 = tanhf(fmaxf(t1 + b1[0], 0.f));
        t2 = tanhf(fmaxf(t2 + b2[0], 0.f));
        amap_s[lane] = t1 + t2;
    }
    __syncthreads();
    if (!valid) return;
    float av = amap_s[lane];
    int gh = h * GH / s, gw = w * GW / s;
    const float* bb = bsf + (size_t)b * C_ * GP + gh * GW + gw;
    const float* xp = x + ((size_t)b * C_ + grp * 64) * ss_ + pix;
    float* op = out + ((size_t)b * C_ + grp * 64) * ss_ + pix;
#pragma unroll 4
    for (int ci = 0; ci < 64; ++ci) {
        int c = grp * 64 + ci;
        op[(size_t)ci * ss_] = xp[(size_t)ci * ss_] + bb[(size_t)c * GP] * av;
    }
}

extern "C" void kernel_launch(void* const* d_in, const int* in_sizes, int n_in,
                              void* d_out, int out_size, void* d_ws, size_t ws_size,
                              hipStream_t stream) {
    const float* x[5];
    for (int i = 0; i < 5; ++i) x[i] = (const float*)d_in[i];
    const float* w_red1 = (const float*)d_in[5];
    const float* b_red1 = (const float*)d_in[6];
    const float* w_red2 = (const float*)d_in[7];
    const float* b_red2 = (const float*)d_in[8];
    const float* w_pts_conv = (const float*)d_in[9];
    const float* b_pts_conv = (const float*)d_in[10];
    const float* w_pts_out = (const float*)d_in[11];
    const float* b_pts_out = (const float*)d_in[12];
    const float* w_refine = (const float*)d_in[13];
    float* out = (float*)d_out;

    // workspace layout
    float* ws = (float*)d_ws;
    float* fe_pm = ws;                     // 1,638,400 f32  [b][pix][c]
    float* p1 = fe_pm + 1638400;           // 1,638,400 f32
    float* pts = p1 + 1638400;             //   115,200 f32
    float* bsf = pts + 115200;             // 1,638,400 f32
    ushort* y_buf = (ushort*)(bsf + 1638400);      // 7,372,800 bf16 (level-0 sized, reused)
    ushort* AS_buf = y_buf + 7372800;              // 14,745,600 bf16 (A1, then S)
    ushort* Wb1 = AS_buf + (size_t)MT * KDIM;      //   589,824 bf16
    ushort* Wb2 = Wb1 + (size_t)C_ * KDIM;         //   589,824 bf16

    static const int SIZES[5] = {160, 80, 40, 20, 10};
    static const size_t OUT_OFF[5] = {0, 26214400, 32768000, 34406400, 34816000};

    fe_kernel<<<dim3(25, 4, B_), 256, 0, stream>>>(x[0], x[1], x[2], x[3], x[4], fe_pm);
    wcvt_kernel<<<2304, 256, 0, stream>>>(w_pts_conv, Wb1);
    wcvt_kernel<<<2304, 256, 0, stream>>>(w_refine, Wb2);
    im2col_kernel<<<MT, 256, 0, stream>>>(fe_pm, AS_buf);
    mfma_gemm<<<dim3(100, 4), 256, 0, stream>>>(AS_buf, Wb1, b_pts_conv, p1);
    pts_kernel<<<450, 256, 0, stream>>>(p1, w_pts_out, b_pts_out, pts);
    sample_kernel<<<MT, 256, 0, stream>>>(fe_pm, pts, AS_buf);   // overwrites A1
    mfma_gemm<<<dim3(100, 4), 256, 0, stream>>>(AS_buf, Wb2, nullptr, bsf);

    for (int i = 0; i < 5; ++i) {
        int s = SIZES[i];
        int npx = B_ * s * s;
        yk_kernel<<<dim3((npx + 255) / 256, 4), 256, 0, stream>>>(
            x[i], w_red1 + (size_t)i * KDIM, w_red2 + (size_t)i * KDIM, y_buf, s);
        fincomb_kernel<<<(npx + 63) / 64, 256, 0, stream>>>(
            x[i], y_buf, b_red1 + i, b_red2 + i, bsf, out + OUT_OFF[i], s);
    }
}

// Round 10
// 280.727 us; speedup vs baseline: 4.9998x; 1.1511x over previous
//
#include <hip/hip_runtime.h>
#include <hip/hip_bf16.h>
#include <math.h>

constexpr int B_ = 4;
constexpr int C_ = 256;
constexpr int GH = 40, GW = 40, GP = 1600;   // refine-level grid
constexpr int KDIM = C_ * 9;                  // 2304
constexpr int MT = B_ * GP;                   // 6400

typedef __attribute__((ext_vector_type(8))) short short8b;   // 8 bf16 (4 VGPRs)
typedef __attribute__((ext_vector_type(4))) float f32x4;

__device__ inline ushort f2b(float f) {
    __hip_bfloat16 h = __float2bfloat16(f);
    return *reinterpret_cast<ushort*>(&h);
}
__device__ inline float b2f(ushort u) {
    unsigned v = (unsigned)u << 16;
    return *reinterpret_cast<float*>(&v);
}

// ---- Stage 1: ori_fe (PIXEL-MAJOR [b][pix][c]) via LDS transpose ----------------
__global__ __launch_bounds__(256) void fe_kernel(const float* __restrict__ x0,
                                                 const float* __restrict__ x1,
                                                 const float* __restrict__ x2,
                                                 const float* __restrict__ x3,
                                                 const float* __restrict__ x4,
                                                 float* __restrict__ fe_pm) {
    __shared__ float tile[64][65];
    int pix0 = blockIdx.x * 64;
    int c0 = blockIdx.y * 64;
    int b = blockIdx.z;
    int lx = threadIdx.x & 63;   // pixel lane
    int ly = threadIdx.x >> 6;   // 4 rows

    int pix = pix0 + lx;
    int h = pix / GW, w = pix - (pix / GW) * GW;
#pragma unroll
    for (int r = 0; r < 64; r += 4) {
        int c = c0 + ly + r;
        size_t bc = (size_t)b * C_ + c;
        const float* p0 = x0 + bc * 25600;
        float m0 = -INFINITY;
#pragma unroll
        for (int dy = 0; dy < 4; ++dy)
#pragma unroll
            for (int dx = 0; dx < 4; ++dx)
                m0 = fmaxf(m0, p0[(4 * h + dy) * 160 + 4 * w + dx]);
        const float* p1 = x1 + bc * 6400;
        float m1 = -INFINITY;
#pragma unroll
        for (int dy = 0; dy < 2; ++dy)
#pragma unroll
            for (int dx = 0; dx < 2; ++dx)
                m1 = fmaxf(m1, p1[(2 * h + dy) * 80 + 2 * w + dx]);
        float v2 = x2[bc * GP + pix];
        float v3 = x3[bc * 400 + (h / 2) * 20 + (w / 2)];
        float v4 = x4[bc * 100 + (h / 4) * 10 + (w / 4)];
        tile[ly + r][lx] = (m0 + m1 + v2 + v3 + v4) * 0.2f;
    }
    __syncthreads();
#pragma unroll
    for (int r = 0; r < 64; r += 4) {
        int p = ly + r;
        fe_pm[((size_t)b * GP + pix0 + p) * C_ + c0 + lx] = tile[lx][p];
    }
}

// ---- weight permute+convert (both weights in one launch) ------------------------
__global__ void wcvt_kernel(const float* __restrict__ wA, const float* __restrict__ wB,
                            ushort* __restrict__ oA, ushort* __restrict__ oB) {
    const float* w = blockIdx.y ? wB : wA;
    ushort* out = blockIdx.y ? oB : oA;
    int idx = blockIdx.x * 256 + threadIdx.x;   // 256*2304
    int o = idx / KDIM;
    int rem = idx - o * KDIM;
    int c = rem / 9, t = rem - c * 9;
    out[(size_t)o * KDIM + t * 256 + c] = f2b(w[idx]);
}

// ---- implicit-A bf16 MFMA GEMM ---------------------------------------------------
// MODE 0: A[m][t*256+c] = im2col(fe_pm) built in registers during staging.
// MODE 1: A[m][t*256+c] = bilinear-sample(fe_pm, pts) built in registers.
// C[b][n][m] = relu(sum_k A*W (+bias)); W[n][k] bf16 (t-major k).
template <int MODE>
__global__ __launch_bounds__(256) void mfma_gemm(const float* __restrict__ fe_pm,
                                                 const float* __restrict__ pts,
                                                 const ushort* __restrict__ Bw,
                                                 const float* __restrict__ bias,
                                                 float* __restrict__ Cout) {
    __shared__ ushort As[64 * 64];
    __shared__ ushort Bs[64 * 64];
    int tid = threadIdx.x;
    int lane = tid & 63;
    int wid = tid >> 6;
    int wm = wid >> 1, wn = wid & 1;
    int m0 = blockIdx.x * 64;
    int n0 = blockIdx.y * 64;
    int b = m0 / GP;
    int pix0 = m0 - b * GP;     // 1600 % 64 == 0 -> tile never crosses batch

    int rw = tid >> 2;          // staging row 0..63
    int q = tid & 3;            // 16-float segment within row
    int so0 = ((2 * q) ^ (rw & 7)) * 8;       // swizzled short offsets (two 16B slots)
    int so1 = ((2 * q + 1) ^ (rw & 7)) * 8;

    int pix = pix0 + rw;
    int h = pix / GW, w = pix - (pix / GW) * GW;
    const float* fb = fe_pm + (size_t)b * GP * C_;
    const float* pb = pts + (size_t)b * 18 * GP + pix;

    f32x4 acc[2][2];
#pragma unroll
    for (int i = 0; i < 2; ++i)
#pragma unroll
        for (int j = 0; j < 2; ++j) acc[i][j] = (f32x4){0.f, 0.f, 0.f, 0.f};

    short8b pa0, pa1, pb0, pb1;

    auto stageA = [&](int k0, short8b& a0, short8b& a1) {
        int t = k0 >> 8;
        int c0 = (k0 & 255) + q * 16;
        float v[16];
        if (MODE == 0) {
            int dy = t / 3 - 1, dx = t - (t / 3) * 3 - 1;
            int yy = h + dy, xx = w + dx;
            if (yy >= 0 && yy < GH && xx >= 0 && xx < GW) {
                const float4* src = (const float4*)(fb + (size_t)(yy * GW + xx) * C_ + c0);
#pragma unroll
                for (int j = 0; j < 4; ++j) {
                    float4 f4 = src[j];
                    v[4 * j] = f4.x; v[4 * j + 1] = f4.y; v[4 * j + 2] = f4.z; v[4 * j + 3] = f4.w;
                }
            } else {
#pragma unroll
                for (int j = 0; j < 16; ++j) v[j] = 0.f;
            }
        } else {
            float py = (float)h + pb[(2 * t) * GP];
            float px = (float)w + pb[(2 * t + 1) * GP];
            float y0f = floorf(py), x0f = floorf(px);
            int y0 = (int)y0f, x0i = (int)x0f;
            float wy1 = py - y0f, wx1 = px - x0f;
            float wy0 = 1.f - wy1, wx0 = 1.f - wx1;
            float wt[4] = {wy0 * wx0, wy0 * wx1, wy1 * wx0, wy1 * wx1};
            int ty[4] = {y0, y0, y0 + 1, y0 + 1};
            int tx[4] = {x0i, x0i + 1, x0i, x0i + 1};
#pragma unroll
            for (int j = 0; j < 16; ++j) v[j] = 0.f;
#pragma unroll
            for (int tp = 0; tp < 4; ++tp) {
                if (ty[tp] >= 0 && ty[tp] < GH && tx[tp] >= 0 && tx[tp] < GW) {
                    const float4* src =
                        (const float4*)(fb + (size_t)(ty[tp] * GW + tx[tp]) * C_ + c0);
#pragma unroll
                    for (int j = 0; j < 4; ++j) {
                        float4 f4 = src[j];
                        v[4 * j] += wt[tp] * f4.x;
                        v[4 * j + 1] += wt[tp] * f4.y;
                        v[4 * j + 2] += wt[tp] * f4.z;
                        v[4 * j + 3] += wt[tp] * f4.w;
                    }
                }
            }
        }
#pragma unroll
        for (int j = 0; j < 8; ++j) a0[j] = (short)f2b(v[j]);
#pragma unroll
        for (int j = 0; j < 8; ++j) a1[j] = (short)f2b(v[8 + j]);
    };
    auto stageB = [&](int k0, short8b& b0, short8b& b1) {
        const ushort* src = Bw + (size_t)(n0 + rw) * KDIM + k0 + q * 16;
        b0 = *(const short8b*)src;
        b1 = *(const short8b*)(src + 8);
    };

    stageA(0, pa0, pa1);
    stageB(0, pb0, pb1);

    for (int k0 = 0; k0 < KDIM; k0 += 64) {
        __syncthreads();   // previous compute done before LDS overwrite
        *(short8b*)(As + rw * 64 + so0) = pa0;
        *(short8b*)(As + rw * 64 + so1) = pa1;
        *(short8b*)(Bs + rw * 64 + so0) = pb0;
        *(short8b*)(Bs + rw * 64 + so1) = pb1;
        __syncthreads();
        if (k0 + 64 < KDIM) {           // prefetch next chunk; hides under MFMA
            stageA(k0 + 64, pa0, pa1);
            stageB(k0 + 64, pb0, pb1);
        }
#pragma unroll
        for (int kq = 0; kq < 2; ++kq) {
            int k16 = kq * 4 + (lane >> 4);
            short8b af[2], bfr[2];
#pragma unroll
            for (int i = 0; i < 2; ++i) {
                int rA = wm * 32 + i * 16 + (lane & 15);
                af[i] = *(const short8b*)(As + rA * 64 + ((k16 ^ (rA & 7)) * 8));
                int rB = wn * 32 + i * 16 + (lane & 15);
                bfr[i] = *(const short8b*)(Bs + rB * 64 + ((k16 ^ (rB & 7)) * 8));
            }
#pragma unroll
            for (int in = 0; in < 2; ++in)
#pragma unroll
                for (int im = 0; im < 2; ++im)
                    acc[in][im] = __builtin_amdgcn_mfma_f32_16x16x32_bf16(
                        bfr[in], af[im], acc[in][im], 0, 0, 0);
        }
    }

    float* Cb = Cout + (size_t)b * C_ * GP;
#pragma unroll
    for (int in = 0; in < 2; ++in) {
#pragma unroll
        for (int r = 0; r < 4; ++r) {
            int n = n0 + wn * 32 + in * 16 + (lane >> 4) * 4 + r;
            float bv = bias ? bias[n] : 0.f;
#pragma unroll
            for (int im = 0; im < 2; ++im) {
                int m = pix0 + wm * 32 + im * 16 + (lane & 15);
                Cb[(size_t)n * GP + m] = fmaxf(acc[in][im][r] + bv, 0.f);
            }
        }
    }
}

// ---- pts = conv1x1(p1, w_pts_out) + b -------------------------------------------
__global__ void pts_kernel(const float* __restrict__ p1, const float* __restrict__ wpo,
                           const float* __restrict__ bpo, float* __restrict__ pts) {
    int idx = blockIdx.x * 256 + threadIdx.x;   // over B*18*1600
    int pix = idx % GP;
    int p = (idx / GP) % 18;
    int b = idx / (GP * 18);
    const float* pb = p1 + (size_t)b * C_ * GP + pix;
    const float* wp = wpo + p * C_;
    float s = bpo[p];
    for (int c = 0; c < C_; ++c) s += pb[(size_t)c * GP] * wp[c];
    pts[idx] = s;
}

// ---- per-level tables ------------------------------------------------------------
__device__ constexpr int L_S[5] = {160, 80, 40, 20, 10};
__device__ constexpr int L_NPX[5] = {102400, 25600, 6400, 1600, 400};
__device__ constexpr int YK_START[5] = {0, 400, 500, 525, 532};      // 534 blocks total
__device__ constexpr int FC_START[5] = {0, 1600, 2000, 2100, 2125};  // 2132 blocks total
__device__ constexpr size_t L_YBASE[5] = {0, 7372800, 9216000, 9676800, 9792000};
__device__ constexpr size_t L_OUT[5] = {0, 26214400, 32768000, 34406400, 34816000};

__device__ inline int lvl_of(int bx, const int* start) {
    return (bx >= start[4]) ? 4 : (bx >= start[3]) ? 3 : (bx >= start[2]) ? 2
           : (bx >= start[1]) ? 1 : 0;
}

// ---- att pass 1 (ALL levels): y[g][conv*9+t][bp] = sum_{c in grp} w[c,t]*x[c,bp] --
__global__ __launch_bounds__(256) void yk_all(const float* __restrict__ x0,
                                              const float* __restrict__ x1,
                                              const float* __restrict__ x2,
                                              const float* __restrict__ x3,
                                              const float* __restrict__ x4,
                                              const float* __restrict__ w_red1,
                                              const float* __restrict__ w_red2,
                                              ushort* __restrict__ y_all) {
    int bx = blockIdx.x;
    int lvl = lvl_of(bx, YK_START);
    const float* x = lvl == 0 ? x0 : lvl == 1 ? x1 : lvl == 2 ? x2 : lvl == 3 ? x3 : x4;
    int s = L_S[lvl];
    int npx = L_NPX[lvl];
    int bp = (bx - YK_START[lvl]) * 256 + threadIdx.x;
    int g = blockIdx.y;
    if (bp >= npx) return;
    int ss_ = s * s;
    int b = bp / ss_;
    int p = bp - b * ss_;
    const float* xg = x + ((size_t)b * C_ + g * 64) * ss_ + p;
    const float* w1g = w_red1 + (size_t)lvl * KDIM + g * 64 * 9;
    const float* w2g = w_red2 + (size_t)lvl * KDIM + g * 64 * 9;
    float a1[9] = {}, a2[9] = {};
#pragma unroll 4
    for (int ci = 0; ci < 64; ++ci) {
        float v = xg[(size_t)ci * ss_];
#pragma unroll
        for (int t = 0; t < 9; ++t) {
            a1[t] += w1g[ci * 9 + t] * v;
            a2[t] += w2g[ci * 9 + t] * v;
        }
    }
    ushort* yb = y_all + L_YBASE[lvl] + bp;
#pragma unroll
    for (int t = 0; t < 9; ++t) {
        yb[(size_t)(g * 18 + t) * npx] = f2b(a1[t]);
        yb[(size_t)(g * 18 + 9 + t) * npx] = f2b(a2[t]);
    }
}

// ---- att pass 2 + combine (ALL levels) -------------------------------------------
__global__ __launch_bounds__(256) void fincomb_all(const float* __restrict__ x0,
                                                   const float* __restrict__ x1,
                                                   const float* __restrict__ x2,
                                                   const float* __restrict__ x3,
                                                   const float* __restrict__ x4,
                                                   const ushort* __restrict__ y_all,
                                                   const float* __restrict__ b_red1,
                                                   const float* __restrict__ b_red2,
                                                   const float* __restrict__ bsf,
                                                   float* __restrict__ out) {
    __shared__ float red[2][4][64];
    __shared__ float amap_s[64];
    int bx = blockIdx.x;
    int lvl = lvl_of(bx, FC_START);
    const float* x = lvl == 0 ? x0 : lvl == 1 ? x1 : lvl == 2 ? x2 : lvl == 3 ? x3 : x4;
    int s = L_S[lvl];
    int npx = L_NPX[lvl];
    const ushort* y = y_all + L_YBASE[lvl];
    float* out_l = out + L_OUT[lvl];
    int lane = threadIdx.x & 63;
    int grp = threadIdx.x >> 6;
    int pix_g = (bx - FC_START[lvl]) * 64 + lane;
    bool valid = pix_g < npx;
    int pg = valid ? pix_g : 0;
    int ss_ = s * s;
    int b = pg / ss_;
    int pix = pg - b * ss_;
    int h = pix / s, w = pix - h * s;
    const ushort* yg = y + (size_t)grp * 18 * npx;
    float s1 = 0.f, s2 = 0.f;
#pragma unroll
    for (int t = 0; t < 9; ++t) {
        int dy = t / 3 - 1, dx = t % 3 - 1;
        int hy = h + dy, wx = w + dx;
        if (hy >= 0 && hy < s && wx >= 0 && wx < s) {
            int qq = pg + dy * s + dx;
            s1 += b2f(yg[(size_t)t * npx + qq]);
            s2 += b2f(yg[(size_t)(9 + t) * npx + qq]);
        }
    }
    red[0][grp][lane] = s1;
    red[1][grp][lane] = s2;
    __syncthreads();
    if (grp == 0) {
        float t1 = red[0][0][lane] + red[0][1][lane] + red[0][2][lane] + red[0][3][lane];
        float t2 = red[1][0][lane] + red[1][1][lane] + red[1][2][lane] + red[1][3][lane];
        t1 = tanhf(fmaxf(t1 + b_red1[lvl], 0.f));
        t2 = tanhf(fmaxf(t2 + b_red2[lvl], 0.f));
        amap_s[lane] = t1 + t2;
    }
    __syncthreads();
    if (!valid) return;
    float av = amap_s[lane];
    int gh = h * GH / s, gw = w * GW / s;
    const float* bb = bsf + (size_t)b * C_ * GP + gh * GW + gw;
    const float* xp = x + ((size_t)b * C_ + grp * 64) * ss_ + pix;
    float* op = out_l + ((size_t)b * C_ + grp * 64) * ss_ + pix;
#pragma unroll 4
    for (int ci = 0; ci < 64; ++ci) {
        int c = grp * 64 + ci;
        op[(size_t)ci * ss_] = xp[(size_t)ci * ss_] + bb[(size_t)c * GP] * av;
    }
}

extern "C" void kernel_launch(void* const* d_in, const int* in_sizes, int n_in,
                              void* d_out, int out_size, void* d_ws, size_t ws_size,
                              hipStream_t stream) {
    const float* x[5];
    for (int i = 0; i < 5; ++i) x[i] = (const float*)d_in[i];
    const float* w_red1 = (const float*)d_in[5];
    const float* b_red1 = (const float*)d_in[6];
    const float* w_red2 = (const float*)d_in[7];
    const float* b_red2 = (const float*)d_in[8];
    const float* w_pts_conv = (const float*)d_in[9];
    const float* b_pts_conv = (const float*)d_in[10];
    const float* w_pts_out = (const float*)d_in[11];
    const float* b_pts_out = (const float*)d_in[12];
    const float* w_refine = (const float*)d_in[13];
    float* out = (float*)d_out;

    // workspace layout
    float* ws = (float*)d_ws;
    float* fe_pm = ws;                     // 1,638,400 f32  [b][pix][c]
    float* p1 = fe_pm + 1638400;           // 1,638,400 f32
    float* pts = p1 + 1638400;             //   115,200 f32
    float* bsf = pts + 115200;             // 1,638,400 f32
    ushort* y_all = (ushort*)(bsf + 1638400);      // 9,820,800 bf16 (all levels)
    ushort* Wb1 = y_all + 9820800;                 //   589,824 bf16
    ushort* Wb2 = Wb1 + (size_t)C_ * KDIM;         //   589,824 bf16
    // total ~42.5 MB

    fe_kernel<<<dim3(25, 4, B_), 256, 0, stream>>>(x[0], x[1], x[2], x[3], x[4], fe_pm);
    wcvt_kernel<<<dim3(2304, 2), 256, 0, stream>>>(w_pts_conv, w_refine, Wb1, Wb2);
    mfma_gemm<0><<<dim3(100, 4), 256, 0, stream>>>(fe_pm, nullptr, Wb1, b_pts_conv, p1);
    pts_kernel<<<450, 256, 0, stream>>>(p1, w_pts_out, b_pts_out, pts);
    mfma_gemm<1><<<dim3(100, 4), 256, 0, stream>>>(fe_pm, pts, Wb2, nullptr, bsf);
    yk_all<<<dim3(534, 4), 256, 0, stream>>>(x[0], x[1], x[2], x[3], x[4],
                                             w_red1, w_red2, y_all);
    fincomb_all<<<2132, 256, 0, stream>>>(x[0], x[1], x[2], x[3], x[4], y_all,
                                          b_red1, b_red2, bsf, out);
}

// Round 12
// 279.026 us; speedup vs baseline: 5.0303x; 1.0061x over previous
//
#include <hip/hip_runtime.h>
#include <hip/hip_bf16.h>
#include <math.h>

constexpr int B_ = 4;
constexpr int C_ = 256;
constexpr int GH = 40, GW = 40, GP = 1600;   // refine-level grid
constexpr int KDIM = C_ * 9;                  // 2304
constexpr int KSPL = 768;                     // K per split (3 taps x 256)
constexpr int NELEM = B_ * C_ * GP;           // 1,638,400 elems per C buffer

typedef __attribute__((ext_vector_type(8))) short short8b;   // 8 bf16 (4 VGPRs)
typedef __attribute__((ext_vector_type(4))) float f32x4;

__device__ inline ushort f2b(float f) {
    __hip_bfloat16 h = __float2bfloat16(f);
    return *reinterpret_cast<ushort*>(&h);
}
__device__ inline float b2f(ushort u) {
    unsigned v = (unsigned)u << 16;
    return *reinterpret_cast<float*>(&v);
}

// ---- Stage 1: ori_fe (PIXEL-MAJOR [b][pix][c]) via LDS transpose ----------------
__global__ __launch_bounds__(256) void fe_kernel(const float* __restrict__ x0,
                                                 const float* __restrict__ x1,
                                                 const float* __restrict__ x2,
                                                 const float* __restrict__ x3,
                                                 const float* __restrict__ x4,
                                                 float* __restrict__ fe_pm) {
    __shared__ float tile[64][65];
    int pix0 = blockIdx.x * 64;
    int c0 = blockIdx.y * 64;
    int b = blockIdx.z;
    int lx = threadIdx.x & 63;   // pixel lane
    int ly = threadIdx.x >> 6;   // 4 rows

    int pix = pix0 + lx;
    int h = pix / GW, w = pix - (pix / GW) * GW;
#pragma unroll
    for (int r = 0; r < 64; r += 4) {
        int c = c0 + ly + r;
        size_t bc = (size_t)b * C_ + c;
        const float* p0 = x0 + bc * 25600;
        float m0 = -INFINITY;
#pragma unroll
        for (int dy = 0; dy < 4; ++dy)
#pragma unroll
            for (int dx = 0; dx < 4; ++dx)
                m0 = fmaxf(m0, p0[(4 * h + dy) * 160 + 4 * w + dx]);
        const float* p1 = x1 + bc * 6400;
        float m1 = -INFINITY;
#pragma unroll
        for (int dy = 0; dy < 2; ++dy)
#pragma unroll
            for (int dx = 0; dx < 2; ++dx)
                m1 = fmaxf(m1, p1[(2 * h + dy) * 80 + 2 * w + dx]);
        float v2 = x2[bc * GP + pix];
        float v3 = x3[bc * 400 + (h / 2) * 20 + (w / 2)];
        float v4 = x4[bc * 100 + (h / 4) * 10 + (w / 4)];
        tile[ly + r][lx] = (m0 + m1 + v2 + v3 + v4) * 0.2f;
    }
    __syncthreads();
#pragma unroll
    for (int r = 0; r < 64; r += 4) {
        int p = ly + r;
        fe_pm[((size_t)b * GP + pix0 + p) * C_ + c0 + lx] = tile[lx][p];
    }
}

// ---- weight permute+convert (both weights in one launch) ------------------------
__global__ void wcvt_kernel(const float* __restrict__ wA, const float* __restrict__ wB,
                            ushort* __restrict__ oA, ushort* __restrict__ oB) {
    const float* w = blockIdx.y ? wB : wA;
    ushort* out = blockIdx.y ? oB : oA;
    int idx = blockIdx.x * 256 + threadIdx.x;   // 256*2304
    int o = idx / KDIM;
    int rem = idx - o * KDIM;
    int c = rem / 9, t = rem - c * 9;
    out[(size_t)o * KDIM + t * 256 + c] = f2b(w[idx]);
}

// ---- implicit-A bf16 MFMA GEMM, K-split x3, LDS double-buffered -----------------
// MODE 0: A = im2col(fe_pm); MODE 1: A = bilinear-sample(fe_pm, pts).
// blockIdx.z = tap-group (3 taps = 768 K). Writes PARTIAL sums (no bias/relu).
template <int MODE>
__global__ __launch_bounds__(256) void mfma_gemm(const float* __restrict__ fe_pm,
                                                 const float* __restrict__ pts,
                                                 const ushort* __restrict__ Bw,
                                                 float* __restrict__ Cpart) {
    __shared__ ushort As[2][64 * 64];
    __shared__ ushort Bs[2][64 * 64];
    int tid = threadIdx.x;
    int lane = tid & 63;
    int wid = tid >> 6;
    int wm = wid >> 1, wn = wid & 1;
    int m0 = blockIdx.x * 64;
    int n0 = blockIdx.y * 64;
    int zs = blockIdx.z;        // tap group
    int b = m0 / GP;
    int pix0 = m0 - b * GP;     // 1600 % 64 == 0 -> tile never crosses batch

    int rw = tid >> 2;          // staging row 0..63
    int q = tid & 3;            // 16-float segment within row
    int so0 = ((2 * q) ^ (rw & 7)) * 8;       // swizzled short offsets (two 16B slots)
    int so1 = ((2 * q + 1) ^ (rw & 7)) * 8;

    int pix = pix0 + rw;
    int h = pix / GW, w = pix - (pix / GW) * GW;
    const float* fb = fe_pm + (size_t)b * GP * C_;
    const float* pb = pts + (size_t)b * 18 * GP + pix;

    f32x4 acc[2][2];
#pragma unroll
    for (int i = 0; i < 2; ++i)
#pragma unroll
        for (int j = 0; j < 2; ++j) acc[i][j] = (f32x4){0.f, 0.f, 0.f, 0.f};

    short8b pa0, pa1, pbv0, pbv1;

    auto stageA = [&](int k0, short8b& a0, short8b& a1) {
        int t = zs * 3 + (k0 >> 8);
        int c0 = (k0 & 255) + q * 16;
        float v[16];
        if (MODE == 0) {
            int dy = t / 3 - 1, dx = t - (t / 3) * 3 - 1;
            int yy = h + dy, xx = w + dx;
            if (yy >= 0 && yy < GH && xx >= 0 && xx < GW) {
                const float4* src = (const float4*)(fb + (size_t)(yy * GW + xx) * C_ + c0);
#pragma unroll
                for (int j = 0; j < 4; ++j) {
                    float4 f4 = src[j];
                    v[4 * j] = f4.x; v[4 * j + 1] = f4.y; v[4 * j + 2] = f4.z; v[4 * j + 3] = f4.w;
                }
            } else {
#pragma unroll
                for (int j = 0; j < 16; ++j) v[j] = 0.f;
            }
        } else {
            float py = (float)h + pb[(2 * t) * GP];
            float px = (float)w + pb[(2 * t + 1) * GP];
            float y0f = floorf(py), x0f = floorf(px);
            int y0 = (int)y0f, x0i = (int)x0f;
            float wy1 = py - y0f, wx1 = px - x0f;
            float wy0 = 1.f - wy1, wx0 = 1.f - wx1;
            float wt[4] = {wy0 * wx0, wy0 * wx1, wy1 * wx0, wy1 * wx1};
            int ty[4] = {y0, y0, y0 + 1, y0 + 1};
            int tx[4] = {x0i, x0i + 1, x0i, x0i + 1};
#pragma unroll
            for (int j = 0; j < 16; ++j) v[j] = 0.f;
#pragma unroll
            for (int tp = 0; tp < 4; ++tp) {
                if (ty[tp] >= 0 && ty[tp] < GH && tx[tp] >= 0 && tx[tp] < GW) {
                    const float4* src =
                        (const float4*)(fb + (size_t)(ty[tp] * GW + tx[tp]) * C_ + c0);
#pragma unroll
                    for (int j = 0; j < 4; ++j) {
                        float4 f4 = src[j];
                        v[4 * j] += wt[tp] * f4.x;
                        v[4 * j + 1] += wt[tp] * f4.y;
                        v[4 * j + 2] += wt[tp] * f4.z;
                        v[4 * j + 3] += wt[tp] * f4.w;
                    }
                }
            }
        }
#pragma unroll
        for (int j = 0; j < 8; ++j) a0[j] = (short)f2b(v[j]);
#pragma unroll
        for (int j = 0; j < 8; ++j) a1[j] = (short)f2b(v[8 + j]);
    };
    auto stageB = [&](int k0, short8b& b0, short8b& b1) {
        const ushort* src = Bw + (size_t)(n0 + rw) * KDIM + zs * KSPL + k0 + q * 16;
        b0 = *(const short8b*)src;
        b1 = *(const short8b*)(src + 8);
    };
    auto lds_write = [&](int buf, short8b a0, short8b a1, short8b b0, short8b b1) {
        *(short8b*)(As[buf] + rw * 64 + so0) = a0;
        *(short8b*)(As[buf] + rw * 64 + so1) = a1;
        *(short8b*)(Bs[buf] + rw * 64 + so0) = b0;
        *(short8b*)(Bs[buf] + rw * 64 + so1) = b1;
    };

    // prologue: fill buffer 0
    stageA(0, pa0, pa1);
    stageB(0, pbv0, pbv1);
    lds_write(0, pa0, pa1, pbv0, pbv1);
    __syncthreads();

    constexpr int NCH = KSPL / 64;   // 12 chunks
    for (int kc = 0; kc < NCH; ++kc) {
        int cur = kc & 1;
        if (kc + 1 < NCH) {           // issue next chunk's loads; fly under MFMA
            stageA((kc + 1) * 64, pa0, pa1);
            stageB((kc + 1) * 64, pbv0, pbv1);
        }
#pragma unroll
        for (int kq = 0; kq < 2; ++kq) {
            int k16 = kq * 4 + (lane >> 4);
            short8b af[2], bfr[2];
#pragma unroll
            for (int i = 0; i < 2; ++i) {
                int rA = wm * 32 + i * 16 + (lane & 15);
                af[i] = *(const short8b*)(As[cur] + rA * 64 + ((k16 ^ (rA & 7)) * 8));
                int rB = wn * 32 + i * 16 + (lane & 15);
                bfr[i] = *(const short8b*)(Bs[cur] + rB * 64 + ((k16 ^ (rB & 7)) * 8));
            }
#pragma unroll
            for (int in = 0; in < 2; ++in)
#pragma unroll
                for (int im = 0; im < 2; ++im)
                    acc[in][im] = __builtin_amdgcn_mfma_f32_16x16x32_bf16(
                        bfr[in], af[im], acc[in][im], 0, 0, 0);
        }
        if (kc + 1 < NCH) lds_write(cur ^ 1, pa0, pa1, pbv0, pbv1);
        __syncthreads();
    }

    float* Cb = Cpart + (size_t)zs * NELEM + (size_t)b * C_ * GP;
#pragma unroll
    for (int in = 0; in < 2; ++in) {
#pragma unroll
        for (int r = 0; r < 4; ++r) {
            int n = n0 + wn * 32 + in * 16 + (lane >> 4) * 4 + r;
#pragma unroll
            for (int im = 0; im < 2; ++im) {
                int m = pix0 + wm * 32 + im * 16 + (lane & 15);
                Cb[(size_t)n * GP + m] = acc[in][im][r];
            }
        }
    }
}

// ---- reduce 3 partials + bias + relu --------------------------------------------
__global__ __launch_bounds__(256) void reduce3_kernel(const float* __restrict__ parts,
                                                      const float* __restrict__ bias,
                                                      float* __restrict__ dst) {
    int idx = blockIdx.x * 256 + threadIdx.x;   // NELEM
    float v = parts[idx] + parts[idx + NELEM] + parts[idx + 2 * NELEM];
    if (bias) v += bias[(idx / GP) & 255];
    dst[idx] = fmaxf(v, 0.f);
}

// ---- pts = conv1x1(p1, w_pts_out) + b -------------------------------------------
__global__ void pts_kernel(const float* __restrict__ p1, const float* __restrict__ wpo,
                           const float* __restrict__ bpo, float* __restrict__ pts) {
    int idx = blockIdx.x * 256 + threadIdx.x;   // over B*18*1600
    int pix = idx % GP;
    int p = (idx / GP) % 18;
    int b = idx / (GP * 18);
    const float* pb = p1 + (size_t)b * C_ * GP + pix;
    const float* wp = wpo + p * C_;
    float s = bpo[p];
    for (int c = 0; c < C_; ++c) s += pb[(size_t)c * GP] * wp[c];
    pts[idx] = s;
}

// ---- per-level tables ------------------------------------------------------------
__device__ constexpr int L_S[5] = {160, 80, 40, 20, 10};
__device__ constexpr int L_NPX[5] = {102400, 25600, 6400, 1600, 400};
__device__ constexpr int YK_START[5] = {0, 400, 500, 525, 532};      // 534 blocks total
__device__ constexpr int FC_START[5] = {0, 1600, 2000, 2100, 2125};  // 2132 blocks total
__device__ constexpr size_t L_YBASE[5] = {0, 7372800, 9216000, 9676800, 9792000};
__device__ constexpr size_t L_OUT[5] = {0, 26214400, 32768000, 34406400, 34816000};

__device__ inline int lvl_of(int bx, const int* start) {
    return (bx >= start[4]) ? 4 : (bx >= start[3]) ? 3 : (bx >= start[2]) ? 2
           : (bx >= start[1]) ? 1 : 0;
}

// ---- att pass 1 (ALL levels): y[g][conv*9+t][bp] = sum_{c in grp} w[c,t]*x[c,bp] --
__global__ __launch_bounds__(256) void yk_all(const float* __restrict__ x0,
                                              const float* __restrict__ x1,
                                              const float* __restrict__ x2,
                                              const float* __restrict__ x3,
                                              const float* __restrict__ x4,
                                              const float* __restrict__ w_red1,
                                              const float* __restrict__ w_red2,
                                              ushort* __restrict__ y_all) {
    int bx = blockIdx.x;
    int lvl = lvl_of(bx, YK_START);
    const float* x = lvl == 0 ? x0 : lvl == 1 ? x1 : lvl == 2 ? x2 : lvl == 3 ? x3 : x4;
    int s = L_S[lvl];
    int npx = L_NPX[lvl];
    int bp = (bx - YK_START[lvl]) * 256 + threadIdx.x;
    int g = blockIdx.y;
    if (bp >= npx) return;
    int ss_ = s * s;
    int b = bp / ss_;
    int p = bp - b * ss_;
    const float* xg = x + ((size_t)b * C_ + g * 64) * ss_ + p;
    const float* w1g = w_red1 + (size_t)lvl * KDIM + g * 64 * 9;
    const float* w2g = w_red2 + (size_t)lvl * KDIM + g * 64 * 9;
    float a1[9] = {}, a2[9] = {};
#pragma unroll 4
    for (int ci = 0; ci < 64; ++ci) {
        float v = xg[(size_t)ci * ss_];
#pragma unroll
        for (int t = 0; t < 9; ++t) {
            a1[t] += w1g[ci * 9 + t] * v;
            a2[t] += w2g[ci * 9 + t] * v;
        }
    }
    ushort* yb = y_all + L_YBASE[lvl] + bp;
#pragma unroll
    for (int t = 0; t < 9; ++t) {
        yb[(size_t)(g * 18 + t) * npx] = f2b(a1[t]);
        yb[(size_t)(g * 18 + 9 + t) * npx] = f2b(a2[t]);
    }
}

// ---- att pass 2 + combine (ALL levels) -------------------------------------------
__global__ __launch_bounds__(256) void fincomb_all(const float* __restrict__ x0,
                                                   const float* __restrict__ x1,
                                                   const float* __restrict__ x2,
                                                   const float* __restrict__ x3,
                                                   const float* __restrict__ x4,
                                                   const ushort* __restrict__ y_all,
                                                   const float* __restrict__ b_red1,
                                                   const float* __restrict__ b_red2,
                                                   const float* __restrict__ bsf,
                                                   float* __restrict__ out) {
    __shared__ float red[2][4][64];
    __shared__ float amap_s[64];
    int bx = blockIdx.x;
    int lvl = lvl_of(bx, FC_START);
    const float* x = lvl == 0 ? x0 : lvl == 1 ? x1 : lvl == 2 ? x2 : lvl == 3 ? x3 : x4;
    int s = L_S[lvl];
    int npx = L_NPX[lvl];
    const ushort* y = y_all + L_YBASE[lvl];
    float* out_l = out + L_OUT[lvl];
    int lane = threadIdx.x & 63;
    int grp = threadIdx.x >> 6;
    int pix_g = (bx - FC_START[lvl]) * 64 + lane;
    bool valid = pix_g < npx;
    int pg = valid ? pix_g : 0;
    int ss_ = s * s;
    int b = pg / ss_;
    int pix = pg - b * ss_;
    int h = pix / s, w = pix - h * s;
    const ushort* yg = y + (size_t)grp * 18 * npx;
    float s1 = 0.f, s2 = 0.f;
#pragma unroll
    for (int t = 0; t < 9; ++t) {
        int dy = t / 3 - 1, dx = t % 3 - 1;
        int hy = h + dy, wx = w + dx;
        if (hy >= 0 && hy < s && wx >= 0 && wx < s) {
            int qq = pg + dy * s + dx;
            s1 += b2f(yg[(size_t)t * npx + qq]);
            s2 += b2f(yg[(size_t)(9 + t) * npx + qq]);
        }
    }
    red[0][grp][lane] = s1;
    red[1][grp][lane] = s2;
    __syncthreads();
    if (grp == 0) {
        float t1 = red[0][0][lane] + red[0][1][lane] + red[0][2][lane] + red[0][3][lane];
        float t2 = red[1][0][lane] + red[1][1][lane] + red[1][2][lane] + red[1][3][lane];
        t1 = tanhf(fmaxf(t1 + b_red1[lvl], 0.f));
        t2 = tanhf(fmaxf(t2 + b_red2[lvl], 0.f));
        amap_s[lane] = t1 + t2;
    }
    __syncthreads();
    if (!valid) return;
    float av = amap_s[lane];
    int gh = h * GH / s, gw = w * GW / s;
    const float* bb = bsf + (size_t)b * C_ * GP + gh * GW + gw;
    const float* xp = x + ((size_t)b * C_ + grp * 64) * ss_ + pix;
    float* op = out_l + ((size_t)b * C_ + grp * 64) * ss_ + pix;
#pragma unroll 4
    for (int ci = 0; ci < 64; ++ci) {
        int c = grp * 64 + ci;
        op[(size_t)ci * ss_] = xp[(size_t)ci * ss_] + bb[(size_t)c * GP] * av;
    }
}

extern "C" void kernel_launch(void* const* d_in, const int* in_sizes, int n_in,
                              void* d_out, int out_size, void* d_ws, size_t ws_size,
                              hipStream_t stream) {
    const float* x[5];
    for (int i = 0; i < 5; ++i) x[i] = (const float*)d_in[i];
    const float* w_red1 = (const float*)d_in[5];
    const float* b_red1 = (const float*)d_in[6];
    const float* w_red2 = (const float*)d_in[7];
    const float* b_red2 = (const float*)d_in[8];
    const float* w_pts_conv = (const float*)d_in[9];
    const float* b_pts_conv = (const float*)d_in[10];
    const float* w_pts_out = (const float*)d_in[11];
    const float* b_pts_out = (const float*)d_in[12];
    const float* w_refine = (const float*)d_in[13];
    float* out = (float*)d_out;

    // workspace layout
    float* ws = (float*)d_ws;
    float* fe_pm = ws;                     // 1,638,400 f32  [b][pix][c]
    float* p1 = fe_pm + 1638400;           // 1,638,400 f32
    float* pts = p1 + 1638400;             //   115,200 f32
    float* bsf = pts + 115200;             // 1,638,400 f32
    float* parts = bsf + 1638400;          // 4,915,200 f32 (3 K-split partials, reused)
    ushort* y_all = (ushort*)(parts + 4915200);    // 9,820,800 bf16 (all levels)
    ushort* Wb1 = y_all + 9820800;                 //   589,824 bf16
    ushort* Wb2 = Wb1 + (size_t)C_ * KDIM;         //   589,824 bf16
    // total ~62 MB

    fe_kernel<<<dim3(25, 4, B_), 256, 0, stream>>>(x[0], x[1], x[2], x[3], x[4], fe_pm);
    wcvt_kernel<<<dim3(2304, 2), 256, 0, stream>>>(w_pts_conv, w_refine, Wb1, Wb2);
    mfma_gemm<0><<<dim3(100, 4, 3), 256, 0, stream>>>(fe_pm, nullptr, Wb1, parts);
    reduce3_kernel<<<6400, 256, 0, stream>>>(parts, b_pts_conv, p1);
    pts_kernel<<<450, 256, 0, stream>>>(p1, w_pts_out, b_pts_out, pts);
    mfma_gemm<1><<<dim3(100, 4, 3), 256, 0, stream>>>(fe_pm, pts, Wb2, parts);
    reduce3_kernel<<<6400, 256, 0, stream>>>(parts, nullptr, bsf);
    yk_all<<<dim3(534, 4), 256, 0, stream>>>(x[0], x[1], x[2], x[3], x[4],
                                             w_red1, w_red2, y_all);
    fincomb_all<<<2132, 256, 0, stream>>>(x[0], x[1], x[2], x[3], x[4], y_all,
                                          b_red1, b_red2, bsf, out);
}

// Round 14
// 241.619 us; speedup vs baseline: 5.8091x; 1.1548x over previous
//
#include <hip/hip_runtime.h>
#include <hip/hip_bf16.h>
#include <math.h>

constexpr int B_ = 4;
constexpr int C_ = 256;
constexpr int GH = 40, GW = 40, GP = 1600;   // refine-level grid
constexpr int KDIM = C_ * 9;                  // 2304
constexpr int MT = B_ * GP;                   // 6400

typedef __attribute__((ext_vector_type(8))) short short8b;   // 8 bf16 (4 VGPRs)
typedef __attribute__((ext_vector_type(4))) float f32x4;

__device__ inline ushort f2b(float f) {
    __hip_bfloat16 h = __float2bfloat16(f);
    return *reinterpret_cast<ushort*>(&h);
}
__device__ inline float b2f(ushort u) {
    unsigned v = (unsigned)u << 16;
    return *reinterpret_cast<float*>(&v);
}

// ---- Stage 1: ori_fe (PIXEL-MAJOR [b][pix][c]) via LDS transpose ----------------
__global__ __launch_bounds__(256) void fe_kernel(const float* __restrict__ x0,
                                                 const float* __restrict__ x1,
                                                 const float* __restrict__ x2,
                                                 const float* __restrict__ x3,
                                                 const float* __restrict__ x4,
                                                 float* __restrict__ fe_pm) {
    __shared__ float tile[64][65];
    int pix0 = blockIdx.x * 64;
    int c0 = blockIdx.y * 64;
    int b = blockIdx.z;
    int lx = threadIdx.x & 63;   // pixel lane
    int ly = threadIdx.x >> 6;   // 4 rows

    int pix = pix0 + lx;
    int h = pix / GW, w = pix - (pix / GW) * GW;
#pragma unroll
    for (int r = 0; r < 64; r += 4) {
        int c = c0 + ly + r;
        size_t bc = (size_t)b * C_ + c;
        const float* p0 = x0 + bc * 25600;
        float m0 = -INFINITY;
#pragma unroll
        for (int dy = 0; dy < 4; ++dy)
#pragma unroll
            for (int dx = 0; dx < 4; ++dx)
                m0 = fmaxf(m0, p0[(4 * h + dy) * 160 + 4 * w + dx]);
        const float* p1 = x1 + bc * 6400;
        float m1 = -INFINITY;
#pragma unroll
        for (int dy = 0; dy < 2; ++dy)
#pragma unroll
            for (int dx = 0; dx < 2; ++dx)
                m1 = fmaxf(m1, p1[(2 * h + dy) * 80 + 2 * w + dx]);
        float v2 = x2[bc * GP + pix];
        float v3 = x3[bc * 400 + (h / 2) * 20 + (w / 2)];
        float v4 = x4[bc * 100 + (h / 4) * 10 + (w / 4)];
        tile[ly + r][lx] = (m0 + m1 + v2 + v3 + v4) * 0.2f;
    }
    __syncthreads();
#pragma unroll
    for (int r = 0; r < 64; r += 4) {
        int p = ly + r;
        fe_pm[((size_t)b * GP + pix0 + p) * C_ + c0 + lx] = tile[lx][p];
    }
}

// ---- weight permute+convert (both weights in one launch) ------------------------
__global__ void wcvt_kernel(const float* __restrict__ wA, const float* __restrict__ wB,
                            ushort* __restrict__ oA, ushort* __restrict__ oB) {
    const float* w = blockIdx.y ? wB : wA;
    ushort* out = blockIdx.y ? oB : oA;
    int idx = blockIdx.x * 256 + threadIdx.x;   // 256*2304
    int o = idx / KDIM;
    int rem = idx - o * KDIM;
    int c = rem / 9, t = rem - c * 9;
    out[(size_t)o * KDIM + t * 256 + c] = f2b(w[idx]);
}

// ---- im2col (3x3 pad1 on fe_pm) -> A1[b*1600+pix][t*256+c] bf16 -----------------
__global__ void im2col_kernel(const float* __restrict__ fe_pm, ushort* __restrict__ A1) {
    int pix = blockIdx.x % GP, b = blockIdx.x / GP;
    int c = threadIdx.x;
    const float* fb = fe_pm + (size_t)b * GP * C_;
    ushort* dst = A1 + (size_t)blockIdx.x * KDIM;
    int h = pix / GW, w = pix - (pix / GW) * GW;
#pragma unroll
    for (int t = 0; t < 9; ++t) {
        int y = h + t / 3 - 1, x = w + t % 3 - 1;
        float v = (y >= 0 && y < GH && x >= 0 && x < GW) ? fb[(size_t)(y * GW + x) * C_ + c]
                                                         : 0.f;
        dst[t * 256 + c] = f2b(v);
    }
}

// ---- bilinear sampling (fe_pm) -> S[b*1600+pix][t*256+c] bf16 -------------------
__global__ void sample_kernel(const float* __restrict__ fe_pm, const float* __restrict__ pts,
                              ushort* __restrict__ S) {
    int pix = blockIdx.x % GP, b = blockIdx.x / GP;
    int c = threadIdx.x;
    const float* fb = fe_pm + (size_t)b * GP * C_;
    const float* pb = pts + (size_t)b * 18 * GP + pix;
    ushort* dst = S + (size_t)blockIdx.x * KDIM;
    int h = pix / GW, w = pix - (pix / GW) * GW;
#pragma unroll
    for (int t = 0; t < 9; ++t) {
        float py = (float)h + pb[(2 * t) * GP];
        float px = (float)w + pb[(2 * t + 1) * GP];
        float y0f = floorf(py), x0f = floorf(px);
        int y0 = (int)y0f, x0 = (int)x0f;
        float wy1 = py - y0f, wx1 = px - x0f;
        float wy0 = 1.f - wy1, wx0 = 1.f - wx1;
        auto tap = [&](int yy, int xx) -> float {
            return (yy >= 0 && yy < GH && xx >= 0 && xx < GW)
                       ? fb[(size_t)(yy * GW + xx) * C_ + c]
                       : 0.f;
        };
        float v = tap(y0, x0) * wy0 * wx0 + tap(y0, x0 + 1) * wy0 * wx1 +
                  tap(y0 + 1, x0) * wy1 * wx0 + tap(y0 + 1, x0 + 1) * wy1 * wx1;
        dst[t * 256 + c] = f2b(v);
    }
}

// ---- bf16 MFMA GEMM, pure-copy staging, LDS double-buffered, 1 barrier/chunk ----
// A: [6400][2304] bf16 (k-contiguous); W: [256][2304] bf16.
// No arithmetic between global load and ds_write -> vmcnt wait sinks below MFMA.
__global__ __launch_bounds__(256) void mfma_gemm(const ushort* __restrict__ A,
                                                 const ushort* __restrict__ Bw,
                                                 const float* __restrict__ bias,
                                                 float* __restrict__ Cout) {
    __shared__ ushort As[2][64 * 64];
    __shared__ ushort Bs[2][64 * 64];
    int tid = threadIdx.x;
    int lane = tid & 63;
    int wid = tid >> 6;
    int wm = wid >> 1, wn = wid & 1;
    int m0 = blockIdx.x * 64;
    int n0 = blockIdx.y * 64;

    int sr = tid >> 3;                  // staging row 0..31 (and +32)
    int ss = tid & 7;                   // logical 16B slot 0..7
    int wsl = (ss ^ (sr & 7)) * 8;      // swizzled short offset within row
    const ushort* gA0 = A + (size_t)(m0 + sr) * KDIM + ss * 8;
    const ushort* gA1 = A + (size_t)(m0 + sr + 32) * KDIM + ss * 8;
    const ushort* gB0 = Bw + (size_t)(n0 + sr) * KDIM + ss * 8;
    const ushort* gB1 = Bw + (size_t)(n0 + sr + 32) * KDIM + ss * 8;

    f32x4 acc[2][2];
#pragma unroll
    for (int i = 0; i < 2; ++i)
#pragma unroll
        for (int j = 0; j < 2; ++j) acc[i][j] = (f32x4){0.f, 0.f, 0.f, 0.f};

    short8b vA0 = *(const short8b*)gA0;
    short8b vA1 = *(const short8b*)gA1;
    short8b vB0 = *(const short8b*)gB0;
    short8b vB1 = *(const short8b*)gB1;
    *(short8b*)(As[0] + sr * 64 + wsl) = vA0;
    *(short8b*)(As[0] + (sr + 32) * 64 + wsl) = vA1;
    *(short8b*)(Bs[0] + sr * 64 + wsl) = vB0;
    *(short8b*)(Bs[0] + (sr + 32) * 64 + wsl) = vB1;
    __syncthreads();

    constexpr int NCH = KDIM / 64;   // 36 chunks
    for (int kc = 0; kc < NCH; ++kc) {
        int cur = kc & 1;
        if (kc + 1 < NCH) {           // issue next chunk's loads; fly under MFMA
            gA0 += 64; gA1 += 64; gB0 += 64; gB1 += 64;
            vA0 = *(const short8b*)gA0;
            vA1 = *(const short8b*)gA1;
            vB0 = *(const short8b*)gB0;
            vB1 = *(const short8b*)gB1;
        }
#pragma unroll
        for (int kq = 0; kq < 2; ++kq) {
            int k16 = kq * 4 + (lane >> 4);
            short8b af[2], bfr[2];
#pragma unroll
            for (int i = 0; i < 2; ++i) {
                int rA = wm * 32 + i * 16 + (lane & 15);
                af[i] = *(const short8b*)(As[cur] + rA * 64 + ((k16 ^ (rA & 7)) * 8));
                int rB = wn * 32 + i * 16 + (lane & 15);
                bfr[i] = *(const short8b*)(Bs[cur] + rB * 64 + ((k16 ^ (rB & 7)) * 8));
            }
#pragma unroll
            for (int in = 0; in < 2; ++in)
#pragma unroll
                for (int im = 0; im < 2; ++im)
                    acc[in][im] = __builtin_amdgcn_mfma_f32_16x16x32_bf16(
                        bfr[in], af[im], acc[in][im], 0, 0, 0);
        }
        if (kc + 1 < NCH) {           // vmcnt wait lands here, after the MFMA block
            *(short8b*)(As[cur ^ 1] + sr * 64 + wsl) = vA0;
            *(short8b*)(As[cur ^ 1] + (sr + 32) * 64 + wsl) = vA1;
            *(short8b*)(Bs[cur ^ 1] + sr * 64 + wsl) = vB0;
            *(short8b*)(Bs[cur ^ 1] + (sr + 32) * 64 + wsl) = vB1;
        }
        __syncthreads();
    }

    int b = m0 / GP;
    int pix0 = m0 - b * GP;     // 1600 % 64 == 0 -> tile never crosses batch
    float* Cb = Cout + (size_t)b * C_ * GP;
#pragma unroll
    for (int in = 0; in < 2; ++in) {
#pragma unroll
        for (int r = 0; r < 4; ++r) {
            int n = n0 + wn * 32 + in * 16 + (lane >> 4) * 4 + r;
            float bv = bias ? bias[n] : 0.f;
#pragma unroll
            for (int im = 0; im < 2; ++im) {
                int m = pix0 + wm * 32 + im * 16 + (lane & 15);
                Cb[(size_t)n * GP + m] = fmaxf(acc[in][im][r] + bv, 0.f);
            }
        }
    }
}

// ---- pts = conv1x1(p1, w_pts_out) + b -------------------------------------------
__global__ void pts_kernel(const float* __restrict__ p1, const float* __restrict__ wpo,
                           const float* __restrict__ bpo, float* __restrict__ pts) {
    int idx = blockIdx.x * 256 + threadIdx.x;   // over B*18*1600
    int pix = idx % GP;
    int p = (idx / GP) % 18;
    int b = idx / (GP * 18);
    const float* pb = p1 + (size_t)b * C_ * GP + pix;
    const float* wp = wpo + p * C_;
    float s = bpo[p];
    for (int c = 0; c < C_; ++c) s += pb[(size_t)c * GP] * wp[c];
    pts[idx] = s;
}

// ---- per-level tables ------------------------------------------------------------
__device__ constexpr int L_S[5] = {160, 80, 40, 20, 10};
__device__ constexpr int L_NPX[5] = {102400, 25600, 6400, 1600, 400};
__device__ constexpr int YK_START[5] = {0, 400, 500, 525, 532};      // 534 blocks total
__device__ constexpr int FC_START[5] = {0, 1600, 2000, 2100, 2125};  // 2132 blocks total
__device__ constexpr size_t L_YBASE[5] = {0, 7372800, 9216000, 9676800, 9792000};
__device__ constexpr size_t L_OUT[5] = {0, 26214400, 32768000, 34406400, 34816000};

__device__ inline int lvl_of(int bx, const int* start) {
    return (bx >= start[4]) ? 4 : (bx >= start[3]) ? 3 : (bx >= start[2]) ? 2
           : (bx >= start[1]) ? 1 : 0;
}

// ---- att pass 1 (ALL levels): y[g][conv*9+t][bp] = sum_{c in grp} w[c,t]*x[c,bp] --
__global__ __launch_bounds__(256) void yk_all(const float* __restrict__ x0,
                                              const float* __restrict__ x1,
                                              const float* __restrict__ x2,
                                              const float* __restrict__ x3,
                                              const float* __restrict__ x4,
                                              const float* __restrict__ w_red1,
                                              const float* __restrict__ w_red2,
                                              ushort* __restrict__ y_all) {
    int bx = blockIdx.x;
    int lvl = lvl_of(bx, YK_START);
    const float* x = lvl == 0 ? x0 : lvl == 1 ? x1 : lvl == 2 ? x2 : lvl == 3 ? x3 : x4;
    int s = L_S[lvl];
    int npx = L_NPX[lvl];
    int bp = (bx - YK_START[lvl]) * 256 + threadIdx.x;
    int g = blockIdx.y;
    if (bp >= npx) return;
    int ss_ = s * s;
    int b = bp / ss_;
    int p = bp - b * ss_;
    const float* xg = x + ((size_t)b * C_ + g * 64) * ss_ + p;
    const float* w1g = w_red1 + (size_t)lvl * KDIM + g * 64 * 9;
    const float* w2g = w_red2 + (size_t)lvl * KDIM + g * 64 * 9;
    float a1[9] = {}, a2[9] = {};
#pragma unroll 4
    for (int ci = 0; ci < 64; ++ci) {
        float v = xg[(size_t)ci * ss_];
#pragma unroll
        for (int t = 0; t < 9; ++t) {
            a1[t] += w1g[ci * 9 + t] * v;
            a2[t] += w2g[ci * 9 + t] * v;
        }
    }
    ushort* yb = y_all + L_YBASE[lvl] + bp;
#pragma unroll
    for (int t = 0; t < 9; ++t) {
        yb[(size_t)(g * 18 + t) * npx] = f2b(a1[t]);
        yb[(size_t)(g * 18 + 9 + t) * npx] = f2b(a2[t]);
    }
}

// ---- att pass 2 + combine (ALL levels) -------------------------------------------
__global__ __launch_bounds__(256) void fincomb_all(const float* __restrict__ x0,
                                                   const float* __restrict__ x1,
                                                   const float* __restrict__ x2,
                                                   const float* __restrict__ x3,
                                                   const float* __restrict__ x4,
                                                   const ushort* __restrict__ y_all,
                                                   const float* __restrict__ b_red1,
                                                   const float* __restrict__ b_red2,
                                                   const float* __restrict__ bsf,
                                                   float* __restrict__ out) {
    __shared__ float red[2][4][64];
    __shared__ float amap_s[64];
    int bx = blockIdx.x;
    int lvl = lvl_of(bx, FC_START);
    const float* x = lvl == 0 ? x0 : lvl == 1 ? x1 : lvl == 2 ? x2 : lvl == 3 ? x3 : x4;
    int s = L_S[lvl];
    int npx = L_NPX[lvl];
    const ushort* y = y_all + L_YBASE[lvl];
    float* out_l = out + L_OUT[lvl];
    int lane = threadIdx.x & 63;
    int grp = threadIdx.x >> 6;
    int pix_g = (bx - FC_START[lvl]) * 64 + lane;
    bool valid = pix_g < npx;
    int pg = valid ? pix_g : 0;
    int ss_ = s * s;
    int b = pg / ss_;
    int pix = pg - b * ss_;
    int h = pix / s, w = pix - h * s;
    const ushort* yg = y + (size_t)grp * 18 * npx;
    float s1 = 0.f, s2 = 0.f;
#pragma unroll
    for (int t = 0; t < 9; ++t) {
        int dy = t / 3 - 1, dx = t % 3 - 1;
        int hy = h + dy, wx = w + dx;
        if (hy >= 0 && hy < s && wx >= 0 && wx < s) {
            int qq = pg + dy * s + dx;
            s1 += b2f(yg[(size_t)t * npx + qq]);
            s2 += b2f(yg[(size_t)(9 + t) * npx + qq]);
        }
    }
    red[0][grp][lane] = s1;
    red[1][grp][lane] = s2;
    __syncthreads();
    if (grp == 0) {
        float t1 = red[0][0][lane] + red[0][1][lane] + red[0][2][lane] + red[0][3][lane];
        float t2 = red[1][0][lane] + red[1][1][lane] + red[1][2][lane] + red[1][3][lane];
        t1 = tanhf(fmaxf(t1 + b_red1[lvl], 0.f));
        t2 = tanhf(fmaxf(t2 + b_red2[lvl], 0.f));
        amap_s[lane] = t1 + t2;
    }
    __syncthreads();
    if (!valid) return;
    float av = amap_s[lane];
    int gh = h * GH / s, gw = w * GW / s;
    const float* bb = bsf + (size_t)b * C_ * GP + gh * GW + gw;
    const float* xp = x + ((size_t)b * C_ + grp * 64) * ss_ + pix;
    float* op = out_l + ((size_t)b * C_ + grp * 64) * ss_ + pix;
#pragma unroll 4
    for (int ci = 0; ci < 64; ++ci) {
        int c = grp * 64 + ci;
        op[(size_t)ci * ss_] = xp[(size_t)ci * ss_] + bb[(size_t)c * GP] * av;
    }
}

extern "C" void kernel_launch(void* const* d_in, const int* in_sizes, int n_in,
                              void* d_out, int out_size, void* d_ws, size_t ws_size,
                              hipStream_t stream) {
    const float* x[5];
    for (int i = 0; i < 5; ++i) x[i] = (const float*)d_in[i];
    const float* w_red1 = (const float*)d_in[5];
    const float* b_red1 = (const float*)d_in[6];
    const float* w_red2 = (const float*)d_in[7];
    const float* b_red2 = (const float*)d_in[8];
    const float* w_pts_conv = (const float*)d_in[9];
    const float* b_pts_conv = (const float*)d_in[10];
    const float* w_pts_out = (const float*)d_in[11];
    const float* b_pts_out = (const float*)d_in[12];
    const float* w_refine = (const float*)d_in[13];
    float* out = (float*)d_out;

    // workspace layout
    float* ws = (float*)d_ws;
    float* fe_pm = ws;                     // 1,638,400 f32  [b][pix][c]
    float* p1 = fe_pm + 1638400;           // 1,638,400 f32
    float* pts = p1 + 1638400;             //   115,200 f32
    float* bsf = pts + 115200;             // 1,638,400 f32
    ushort* y_all = (ushort*)(bsf + 1638400);      // 9,820,800 bf16 (all levels)
    ushort* AS_buf = y_all + 9820800;              // 14,745,600 bf16 (A1, then S)
    ushort* Wb1 = AS_buf + (size_t)MT * KDIM;      //   589,824 bf16
    ushort* Wb2 = Wb1 + (size_t)C_ * KDIM;         //   589,824 bf16
    // total ~71.4 MB

    fe_kernel<<<dim3(25, 4, B_), 256, 0, stream>>>(x[0], x[1], x[2], x[3], x[4], fe_pm);
    wcvt_kernel<<<dim3(2304, 2), 256, 0, stream>>>(w_pts_conv, w_refine, Wb1, Wb2);
    im2col_kernel<<<MT, 256, 0, stream>>>(fe_pm, AS_buf);
    mfma_gemm<<<dim3(100, 4), 256, 0, stream>>>(AS_buf, Wb1, b_pts_conv, p1);
    pts_kernel<<<450, 256, 0, stream>>>(p1, w_pts_out, b_pts_out, pts);
    sample_kernel<<<MT, 256, 0, stream>>>(fe_pm, pts, AS_buf);   // overwrites A1
    mfma_gemm<<<dim3(100, 4), 256, 0, stream>>>(AS_buf, Wb2, nullptr, bsf);
    yk_all<<<dim3(534, 4), 256, 0, stream>>>(x[0], x[1], x[2], x[3], x[4],
                                             w_red1, w_red2, y_all);
    fincomb_all<<<2132, 256, 0, stream>>>(x[0], x[1], x[2], x[3], x[4], y_all,
                                          b_red1, b_red2, bsf, out);
}

// Round 15
// 229.117 us; speedup vs baseline: 6.1260x; 1.0546x over previous
//
#include <hip/hip_runtime.h>
#include <hip/hip_bf16.h>
#include <math.h>

constexpr int B_ = 4;
constexpr int C_ = 256;
constexpr int GH = 40, GW = 40, GP = 1600;   // refine-level grid
constexpr int KDIM = C_ * 9;                  // 2304
constexpr int MT = B_ * GP;                   // 6400

typedef __attribute__((ext_vector_type(8))) short short8b;   // 8 bf16 (4 VGPRs)
typedef __attribute__((ext_vector_type(4))) float f32x4;

__device__ inline ushort f2b(float f) {
    __hip_bfloat16 h = __float2bfloat16(f);
    return *reinterpret_cast<ushort*>(&h);
}
__device__ inline float b2f(ushort u) {
    unsigned v = (unsigned)u << 16;
    return *reinterpret_cast<float*>(&v);
}

// ---- Stage 1: ori_fe (PIXEL-MAJOR [b][pix][c]) via LDS transpose ----------------
__global__ __launch_bounds__(256) void fe_kernel(const float* __restrict__ x0,
                                                 const float* __restrict__ x1,
                                                 const float* __restrict__ x2,
                                                 const float* __restrict__ x3,
                                                 const float* __restrict__ x4,
                                                 float* __restrict__ fe_pm) {
    __shared__ float tile[64][65];
    int pix0 = blockIdx.x * 64;
    int c0 = blockIdx.y * 64;
    int b = blockIdx.z;
    int lx = threadIdx.x & 63;   // pixel lane
    int ly = threadIdx.x >> 6;   // 4 rows

    int pix = pix0 + lx;
    int h = pix / GW, w = pix - (pix / GW) * GW;
#pragma unroll
    for (int r = 0; r < 64; r += 4) {
        int c = c0 + ly + r;
        size_t bc = (size_t)b * C_ + c;
        const float* p0 = x0 + bc * 25600;
        float m0 = -INFINITY;
#pragma unroll
        for (int dy = 0; dy < 4; ++dy)
#pragma unroll
            for (int dx = 0; dx < 4; ++dx)
                m0 = fmaxf(m0, p0[(4 * h + dy) * 160 + 4 * w + dx]);
        const float* p1 = x1 + bc * 6400;
        float m1 = -INFINITY;
#pragma unroll
        for (int dy = 0; dy < 2; ++dy)
#pragma unroll
            for (int dx = 0; dx < 2; ++dx)
                m1 = fmaxf(m1, p1[(2 * h + dy) * 80 + 2 * w + dx]);
        float v2 = x2[bc * GP + pix];
        float v3 = x3[bc * 400 + (h / 2) * 20 + (w / 2)];
        float v4 = x4[bc * 100 + (h / 4) * 10 + (w / 4)];
        tile[ly + r][lx] = (m0 + m1 + v2 + v3 + v4) * 0.2f;
    }
    __syncthreads();
#pragma unroll
    for (int r = 0; r < 64; r += 4) {
        int p = ly + r;
        fe_pm[((size_t)b * GP + pix0 + p) * C_ + c0 + lx] = tile[lx][p];
    }
}

// ---- weight permute+convert (both weights in one launch) ------------------------
__global__ void wcvt_kernel(const float* __restrict__ wA, const float* __restrict__ wB,
                            ushort* __restrict__ oA, ushort* __restrict__ oB) {
    const float* w = blockIdx.y ? wB : wA;
    ushort* out = blockIdx.y ? oB : oA;
    int idx = blockIdx.x * 256 + threadIdx.x;   // 256*2304
    int o = idx / KDIM;
    int rem = idx - o * KDIM;
    int c = rem / 9, t = rem - c * 9;
    out[(size_t)o * KDIM + t * 256 + c] = f2b(w[idx]);
}

// ---- im2col (3x3 pad1 on fe_pm) -> A1[b*1600+pix][t*256+c] bf16 -----------------
__global__ void im2col_kernel(const float* __restrict__ fe_pm, ushort* __restrict__ A1) {
    int pix = blockIdx.x % GP, b = blockIdx.x / GP;
    int c = threadIdx.x;
    const float* fb = fe_pm + (size_t)b * GP * C_;
    ushort* dst = A1 + (size_t)blockIdx.x * KDIM;
    int h = pix / GW, w = pix - (pix / GW) * GW;
#pragma unroll
    for (int t = 0; t < 9; ++t) {
        int y = h + t / 3 - 1, x = w + t % 3 - 1;
        float v = (y >= 0 && y < GH && x >= 0 && x < GW) ? fb[(size_t)(y * GW + x) * C_ + c]
                                                         : 0.f;
        dst[t * 256 + c] = f2b(v);
    }
}

// ---- bilinear sampling (fe_pm) -> S[b*1600+pix][t*256+c] bf16 -------------------
__global__ void sample_kernel(const float* __restrict__ fe_pm, const float* __restrict__ pts,
                              ushort* __restrict__ S) {
    int pix = blockIdx.x % GP, b = blockIdx.x / GP;
    int c = threadIdx.x;
    const float* fb = fe_pm + (size_t)b * GP * C_;
    const float* pb = pts + (size_t)b * 18 * GP + pix;
    ushort* dst = S + (size_t)blockIdx.x * KDIM;
    int h = pix / GW, w = pix - (pix / GW) * GW;
#pragma unroll
    for (int t = 0; t < 9; ++t) {
        float py = (float)h + pb[(2 * t) * GP];
        float px = (float)w + pb[(2 * t + 1) * GP];
        float y0f = floorf(py), x0f = floorf(px);
        int y0 = (int)y0f, x0 = (int)x0f;
        float wy1 = py - y0f, wx1 = px - x0f;
        float wy0 = 1.f - wy1, wx0 = 1.f - wx1;
        auto tap = [&](int yy, int xx) -> float {
            return (yy >= 0 && yy < GH && xx >= 0 && xx < GW)
                       ? fb[(size_t)(yy * GW + xx) * C_ + c]
                       : 0.f;
        };
        float v = tap(y0, x0) * wy0 * wx0 + tap(y0, x0 + 1) * wy0 * wx1 +
                  tap(y0 + 1, x0) * wy1 * wx0 + tap(y0 + 1, x0 + 1) * wy1 * wx1;
        dst[t * 256 + c] = f2b(v);
    }
}

// ---- bf16 MFMA GEMM, pure-copy staging, depth-2 prefetch, dbuf LDS --------------
// A: [6400][2304] bf16 (k-contiguous); W: [256][2304] bf16.
// Two register sets (X,Y): loads for chunk k+2 issued a full chunk before their
// ds_write -> counted vmcnt finds them complete; latency amortized over 2 phases.
__global__ __launch_bounds__(256) void mfma_gemm(const ushort* __restrict__ A,
                                                 const ushort* __restrict__ Bw,
                                                 const float* __restrict__ bias,
                                                 float* __restrict__ Cout) {
    __shared__ ushort As[2][64 * 64];
    __shared__ ushort Bs[2][64 * 64];
    int tid = threadIdx.x;
    int lane = tid & 63;
    int wid = tid >> 6;
    int wm = wid >> 1, wn = wid & 1;
    int m0 = blockIdx.x * 64;
    int n0 = blockIdx.y * 64;

    int sr = tid >> 3;                  // staging row 0..31 (and +32)
    int ss = tid & 7;                   // logical 16B slot 0..7
    int wsl = (ss ^ (sr & 7)) * 8;      // swizzled short offset within row
    const ushort* gA0 = A + (size_t)(m0 + sr) * KDIM + ss * 8;
    const ushort* gA1 = A + (size_t)(m0 + sr + 32) * KDIM + ss * 8;
    const ushort* gB0 = Bw + (size_t)(n0 + sr) * KDIM + ss * 8;
    const ushort* gB1 = Bw + (size_t)(n0 + sr + 32) * KDIM + ss * 8;

    f32x4 acc[2][2];
#pragma unroll
    for (int i = 0; i < 2; ++i)
#pragma unroll
        for (int j = 0; j < 2; ++j) acc[i][j] = (f32x4){0.f, 0.f, 0.f, 0.f};

    short8b xA0, xA1, xB0, xB1;   // register set X
    short8b yA0, yA1, yB0, yB1;   // register set Y

    auto loadX = [&]() {
        xA0 = *(const short8b*)gA0; xA1 = *(const short8b*)gA1;
        xB0 = *(const short8b*)gB0; xB1 = *(const short8b*)gB1;
        gA0 += 64; gA1 += 64; gB0 += 64; gB1 += 64;
    };
    auto loadY = [&]() {
        yA0 = *(const short8b*)gA0; yA1 = *(const short8b*)gA1;
        yB0 = *(const short8b*)gB0; yB1 = *(const short8b*)gB1;
        gA0 += 64; gA1 += 64; gB0 += 64; gB1 += 64;
    };
    auto writeL = [&](int buf, short8b a0, short8b a1, short8b b0, short8b b1) {
        *(short8b*)(As[buf] + sr * 64 + wsl) = a0;
        *(short8b*)(As[buf] + (sr + 32) * 64 + wsl) = a1;
        *(short8b*)(Bs[buf] + sr * 64 + wsl) = b0;
        *(short8b*)(Bs[buf] + (sr + 32) * 64 + wsl) = b1;
    };
    auto compute = [&](int cur) {
#pragma unroll
        for (int kq = 0; kq < 2; ++kq) {
            int k16 = kq * 4 + (lane >> 4);
            short8b af[2], bfr[2];
#pragma unroll
            for (int i = 0; i < 2; ++i) {
                int rA = wm * 32 + i * 16 + (lane & 15);
                af[i] = *(const short8b*)(As[cur] + rA * 64 + ((k16 ^ (rA & 7)) * 8));
                int rB = wn * 32 + i * 16 + (lane & 15);
                bfr[i] = *(const short8b*)(Bs[cur] + rB * 64 + ((k16 ^ (rB & 7)) * 8));
            }
#pragma unroll
            for (int in = 0; in < 2; ++in)
#pragma unroll
                for (int im = 0; im < 2; ++im)
                    acc[in][im] = __builtin_amdgcn_mfma_f32_16x16x32_bf16(
                        bfr[in], af[im], acc[in][im], 0, 0, 0);
        }
    };

    constexpr int NCH = KDIM / 64;   // 36 chunks (even)
    loadX();                          // chunk 0
    loadY();                          // chunk 1
    writeL(0, xA0, xA1, xB0, xB1);
    __syncthreads();

    for (int kc = 0; kc < NCH; kc += 2) {
        // phase A: compute chunk kc (LDS[0]); Y holds kc+1; prefetch kc+2 into X
        if (kc + 2 < NCH) loadX();
        compute(0);
        writeL(1, yA0, yA1, yB0, yB1);     // waits Y (issued one phase-pair ago)
        __syncthreads();
        // phase B: compute chunk kc+1 (LDS[1]); X holds kc+2; prefetch kc+3 into Y
        if (kc + 3 < NCH) loadY();
        compute(1);
        if (kc + 2 < NCH) writeL(0, xA0, xA1, xB0, xB1);
        __syncthreads();
    }

    int b = m0 / GP;
    int pix0 = m0 - b * GP;     // 1600 % 64 == 0 -> tile never crosses batch
    float* Cb = Cout + (size_t)b * C_ * GP;
#pragma unroll
    for (int in = 0; in < 2; ++in) {
#pragma unroll
        for (int r = 0; r < 4; ++r) {
            int n = n0 + wn * 32 + in * 16 + (lane >> 4) * 4 + r;
            float bv = bias ? bias[n] : 0.f;
#pragma unroll
            for (int im = 0; im < 2; ++im) {
                int m = pix0 + wm * 32 + im * 16 + (lane & 15);
                Cb[(size_t)n * GP + m] = fmaxf(acc[in][im][r] + bv, 0.f);
            }
        }
    }
}

// ---- pts = conv1x1(p1, w_pts_out) + b -------------------------------------------
__global__ void pts_kernel(const float* __restrict__ p1, const float* __restrict__ wpo,
                           const float* __restrict__ bpo, float* __restrict__ pts) {
    int idx = blockIdx.x * 256 + threadIdx.x;   // over B*18*1600
    int pix = idx % GP;
    int p = (idx / GP) % 18;
    int b = idx / (GP * 18);
    const float* pb = p1 + (size_t)b * C_ * GP + pix;
    const float* wp = wpo + p * C_;
    float s = bpo[p];
    for (int c = 0; c < C_; ++c) s += pb[(size_t)c * GP] * wp[c];
    pts[idx] = s;
}

// ---- per-level tables ------------------------------------------------------------
__device__ constexpr int L_S[5] = {160, 80, 40, 20, 10};
__device__ constexpr int L_NPX[5] = {102400, 25600, 6400, 1600, 400};
__device__ constexpr int YK_START[5] = {0, 400, 500, 525, 532};      // 534 blocks total
__device__ constexpr int FC_START[5] = {0, 1600, 2000, 2100, 2125};  // 2132 blocks total
__device__ constexpr size_t L_YBASE[5] = {0, 7372800, 9216000, 9676800, 9792000};
__device__ constexpr size_t L_OUT[5] = {0, 26214400, 32768000, 34406400, 34816000};

__device__ inline int lvl_of(int bx, const int* start) {
    return (bx >= start[4]) ? 4 : (bx >= start[3]) ? 3 : (bx >= start[2]) ? 2
           : (bx >= start[1]) ? 1 : 0;
}

// ---- att pass 1 (ALL levels): y[g][conv*9+t][bp] = sum_{c in grp} w[c,t]*x[c,bp] --
__global__ __launch_bounds__(256) void yk_all(const float* __restrict__ x0,
                                              const float* __restrict__ x1,
                                              const float* __restrict__ x2,
                                              const float* __restrict__ x3,
                                              const float* __restrict__ x4,
                                              const float* __restrict__ w_red1,
                                              const float* __restrict__ w_red2,
                                              ushort* __restrict__ y_all) {
    int bx = blockIdx.x;
    int lvl = lvl_of(bx, YK_START);
    const float* x = lvl == 0 ? x0 : lvl == 1 ? x1 : lvl == 2 ? x2 : lvl == 3 ? x3 : x4;
    int s = L_S[lvl];
    int npx = L_NPX[lvl];
    int bp = (bx - YK_START[lvl]) * 256 + threadIdx.x;
    int g = blockIdx.y;
    if (bp >= npx) return;
    int ss_ = s * s;
    int b = bp / ss_;
    int p = bp - b * ss_;
    const float* xg = x + ((size_t)b * C_ + g * 64) * ss_ + p;
    const float* w1g = w_red1 + (size_t)lvl * KDIM + g * 64 * 9;
    const float* w2g = w_red2 + (size_t)lvl * KDIM + g * 64 * 9;
    float a1[9] = {}, a2[9] = {};
#pragma unroll 4
    for (int ci = 0; ci < 64; ++ci) {
        float v = xg[(size_t)ci * ss_];
#pragma unroll
        for (int t = 0; t < 9; ++t) {
            a1[t] += w1g[ci * 9 + t] * v;
            a2[t] += w2g[ci * 9 + t] * v;
        }
    }
    ushort* yb = y_all + L_YBASE[lvl] + bp;
#pragma unroll
    for (int t = 0; t < 9; ++t) {
        yb[(size_t)(g * 18 + t) * npx] = f2b(a1[t]);
        yb[(size_t)(g * 18 + 9 + t) * npx] = f2b(a2[t]);
    }
}

// ---- att pass 2 + combine (ALL levels) -------------------------------------------
__global__ __launch_bounds__(256) void fincomb_all(const float* __restrict__ x0,
                                                   const float* __restrict__ x1,
                                                   const float* __restrict__ x2,
                                                   const float* __restrict__ x3,
                                                   const float* __restrict__ x4,
                                                   const ushort* __restrict__ y_all,
                                                   const float* __restrict__ b_red1,
                                                   const float* __restrict__ b_red2,
                                                   const float* __restrict__ bsf,
                                                   float* __restrict__ out) {
    __shared__ float red[2][4][64];
    __shared__ float amap_s[64];
    int bx = blockIdx.x;
    int lvl = lvl_of(bx, FC_START);
    const float* x = lvl == 0 ? x0 : lvl == 1 ? x1 : lvl == 2 ? x2 : lvl == 3 ? x3 : x4;
    int s = L_S[lvl];
    int npx = L_NPX[lvl];
    const ushort* y = y_all + L_YBASE[lvl];
    float* out_l = out + L_OUT[lvl];
    int lane = threadIdx.x & 63;
    int grp = threadIdx.x >> 6;
    int pix_g = (bx - FC_START[lvl]) * 64 + lane;
    bool valid = pix_g < npx;
    int pg = valid ? pix_g : 0;
    int ss_ = s * s;
    int b = pg / ss_;
    int pix = pg - b * ss_;
    int h = pix / s, w = pix - h * s;
    const ushort* yg = y + (size_t)grp * 18 * npx;
    float s1 = 0.f, s2 = 0.f;
#pragma unroll
    for (int t = 0; t < 9; ++t) {
        int dy = t / 3 - 1, dx = t % 3 - 1;
        int hy = h + dy, wx = w + dx;
        if (hy >= 0 && hy < s && wx >= 0 && wx < s) {
            int qq = pg + dy * s + dx;
            s1 += b2f(yg[(size_t)t * npx + qq]);
            s2 += b2f(yg[(size_t)(9 + t) * npx + qq]);
        }
    }
    red[0][grp][lane] = s1;
    red[1][grp][lane] = s2;
    __syncthreads();
    if (grp == 0) {
        float t1 = red[0][0][lane] + red[0][1][lane] + red[0][2][lane] + red[0][3][lane];
        float t2 = red[1][0][lane] + red[1][1][lane] + red[1][2][lane] + red[1][3][lane];
        t1 = tanhf(fmaxf(t1 + b_red1[lvl], 0.f));
        t2 = tanhf(fmaxf(t2 + b_red2[lvl], 0.f));
        amap_s[lane] = t1 + t2;
    }
    __syncthreads();
    if (!valid) return;
    float av = amap_s[lane];
    int gh = h * GH / s, gw = w * GW / s;
    const float* bb = bsf + (size_t)b * C_ * GP + gh * GW + gw;
    const float* xp = x + ((size_t)b * C_ + grp * 64) * ss_ + pix;
    float* op = out_l + ((size_t)b * C_ + grp * 64) * ss_ + pix;
#pragma unroll 4
    for (int ci = 0; ci < 64; ++ci) {
        int c = grp * 64 + ci;
        op[(size_t)ci * ss_] = xp[(size_t)ci * ss_] + bb[(size_t)c * GP] * av;
    }
}

extern "C" void kernel_launch(void* const* d_in, const int* in_sizes, int n_in,
                              void* d_out, int out_size, void* d_ws, size_t ws_size,
                              hipStream_t stream) {
    const float* x[5];
    for (int i = 0; i < 5; ++i) x[i] = (const float*)d_in[i];
    const float* w_red1 = (const float*)d_in[5];
    const float* b_red1 = (const float*)d_in[6];
    const float* w_red2 = (const float*)d_in[7];
    const float* b_red2 = (const float*)d_in[8];
    const float* w_pts_conv = (const float*)d_in[9];
    const float* b_pts_conv = (const float*)d_in[10];
    const float* w_pts_out = (const float*)d_in[11];
    const float* b_pts_out = (const float*)d_in[12];
    const float* w_refine = (const float*)d_in[13];
    float* out = (float*)d_out;

    // workspace layout
    float* ws = (float*)d_ws;
    float* fe_pm = ws;                     // 1,638,400 f32  [b][pix][c]
    float* p1 = fe_pm + 1638400;           // 1,638,400 f32
    float* pts = p1 + 1638400;             //   115,200 f32
    float* bsf = pts + 115200;             // 1,638,400 f32
    ushort* y_all = (ushort*)(bsf + 1638400);      // 9,820,800 bf16 (all levels)
    ushort* AS_buf = y_all + 9820800;              // 14,745,600 bf16 (A1, then S)
    ushort* Wb1 = AS_buf + (size_t)MT * KDIM;      //   589,824 bf16
    ushort* Wb2 = Wb1 + (size_t)C_ * KDIM;         //   589,824 bf16
    // total ~71.4 MB

    fe_kernel<<<dim3(25, 4, B_), 256, 0, stream>>>(x[0], x[1], x[2], x[3], x[4], fe_pm);
    wcvt_kernel<<<dim3(2304, 2), 256, 0, stream>>>(w_pts_conv, w_refine, Wb1, Wb2);
    im2col_kernel<<<MT, 256, 0, stream>>>(fe_pm, AS_buf);
    mfma_gemm<<<dim3(100, 4), 256, 0, stream>>>(AS_buf, Wb1, b_pts_conv, p1);
    pts_kernel<<<450, 256, 0, stream>>>(p1, w_pts_out, b_pts_out, pts);
    sample_kernel<<<MT, 256, 0, stream>>>(fe_pm, pts, AS_buf);   // overwrites A1
    mfma_gemm<<<dim3(100, 4), 256, 0, stream>>>(AS_buf, Wb2, nullptr, bsf);
    yk_all<<<dim3(534, 4), 256, 0, stream>>>(x[0], x[1], x[2], x[3], x[4],
                                             w_red1, w_red2, y_all);
    fincomb_all<<<2132, 256, 0, stream>>>(x[0], x[1], x[2], x[3], x[4], y_all,
                                          b_red1, b_red2, bsf, out);
}